// Round 9
// baseline (354.818 us; speedup 1.0000x reference)
//
#include <hip/hip_runtime.h>
#include <cfloat>

typedef short  bf16x8 __attribute__((ext_vector_type(8)));
typedef float  f32x4  __attribute__((ext_vector_type(4)));
typedef unsigned int  uint;
typedef unsigned short ushort;

// Problem constants
constexpr int DIM  = 512;
constexpr int NEMB = 1024;
constexpr int HW   = 1024;
constexpr int NROW = 32 * HW;   // 32768

constexpr long long QCOUNT = (long long)32 * 512 * 32 * 32; // 16777216
constexpr long long SOFF   = QCOUNT;
constexpr long long IOFF   = SOFF + 1;

// ---------------- ws layout (bytes) ----------------
// zt: 512 mb x 16 kc tiles of (64r x 32k bf16, swizzled) = 4KB -> 32 MB each
// et: 8 nc x 16 kc tiles of (128r x 32k bf16, swizzled) = 8KB  -> 1 MB each
// cand: per (half, row) candidate {b1,b2} f32x2 + idx i32
constexpr size_t WS_ZHI   = 0;
constexpr size_t WS_ZLO   = 33554432;
constexpr size_t WS_EHI   = 67108864;
constexpr size_t WS_ELO   = 68157440;
constexpr size_t WS_ENORM = 69206016;
constexpr size_t WS_CNT   = 69210112;
constexpr size_t WS_LIST  = 69210368;                          // NROW*4 = 128KB
constexpr size_t WS_CANDB = WS_LIST + (size_t)NROW * 4;        // 2*NROW*8 = 512KB
constexpr size_t WS_CANDI = WS_CANDB + (size_t)2 * NROW * 8;   // 2*NROW*4 = 256KB
constexpr size_t WS_NEED  = WS_CANDI + (size_t)2 * NROW * 4;

constexpr float DELTA = 0.125f;  // recheck margin (>>100x bf16-split error bound)

// ---------------- helpers ----------------
__device__ __forceinline__ ushort bf16_rne(float x) {
    union { float f; uint u; } a; a.f = x;
    uint t = a.u + 0x7FFFu + ((a.u >> 16) & 1u);
    return (ushort)(t >> 16);
}
__device__ __forceinline__ float bf16_to_f(ushort h) {
    union { float f; uint u; } a; a.u = ((uint)h) << 16;
    return a.f;
}
__device__ __forceinline__ void gld16(const void* g, void* l) {
    __builtin_amdgcn_global_load_lds(
        (const __attribute__((address_space(1))) void*)g,
        (__attribute__((address_space(3))) void*)l, 16, 0, 0);
}
union PK8 { bf16x8 v; ushort u[8]; };

// granule swizzle for 32k-wide tiles (row = 64B = 4 x 16B granules):
// proven ~0 conflicts in r7/r8 (23K counts, negligible)
__device__ __forceinline__ int swz_slot(int r, int g) {
    return g ^ ((r >> 1) & 3);
}

// ---------------- P1: embedding norms + counter zero ----------------
__global__ __launch_bounds__(256) void enorm_prep(const float* __restrict__ e,
                                                  float* __restrict__ enorm,
                                                  int* __restrict__ cnt) {
    if (blockIdx.x == 0 && threadIdx.x == 0) *cnt = 0;
    int gid  = blockIdx.x * 256 + threadIdx.x;
    int wave = gid >> 6;
    int lane = gid & 63;
    if (wave >= NEMB) return;
    const float* row = e + (size_t)wave * DIM;
    float4 a = *reinterpret_cast<const float4*>(row + lane * 8);
    float4 b = *reinterpret_cast<const float4*>(row + lane * 8 + 4);
    float s = a.x*a.x + a.y*a.y + a.z*a.z + a.w*a.w
            + b.x*b.x + b.y*b.y + b.z*b.z + b.w*b.w;
    #pragma unroll
    for (int off = 32; off > 0; off >>= 1) s += __shfl_down(s, off, 64);
    if (lane == 0) enorm[wave] = s;
}

// ---------------- P2: e -> et_hi / et_lo swizzled 128x32 tiles -------------
__global__ __launch_bounds__(256) void eprep(const float* __restrict__ e,
                                             char* __restrict__ et_hi,
                                             char* __restrict__ et_lo) {
    int gid = blockIdx.x * 256 + threadIdx.x;  // 0..65535
    int ke  = gid >> 6;                        // embedding row 0..1023
    int kbg = gid & 63;                        // 16B-granule 0..63
    const float* src = e + (size_t)ke * DIM + kbg * 8;
    PK8 h, lo;
    #pragma unroll
    for (int j = 0; j < 8; ++j) {
        float v = src[j];
        ushort hh = bf16_rne(v);
        h.u[j]  = hh;
        lo.u[j] = bf16_rne(v - bf16_to_f(hh));
    }
    int nc = ke >> 7, r = ke & 127, kc = kbg >> 2, g = kbg & 3;
    size_t byte = ((size_t)(nc * 16 + kc)) * 8192 + (size_t)r * 64
                + ((size_t)swz_slot(r, g) << 4);
    *reinterpret_cast<bf16x8*>(et_hi + byte) = h.v;
    *reinterpret_cast<bf16x8*>(et_lo + byte) = lo.v;
}

// ---------------- P3: z -> zt_hi / zt_lo swizzled 64x32 tiles (transpose) --
__global__ __launch_bounds__(256) void zprep(const float* __restrict__ z,
                                             char* __restrict__ zt_hi,
                                             char* __restrict__ zt_lo) {
    __shared__ float ls[64][65];
    const int bx = blockIdx.x;
    const int mb = bx >> 3, kcc = bx & 7;      // kcc: 64-channel group
    const int n0 = mb * 64;
    const int b  = n0 >> 10;
    const int hw0 = n0 & (HW - 1);
    const int t = threadIdx.x;
    const int c4 = t >> 6, lane = t & 63;
    #pragma unroll
    for (int rnd = 0; rnd < 16; ++rnd) {
        int cl = c4 + rnd * 4;
        ls[cl][lane] = z[((size_t)(b * DIM + kcc * 64 + cl)) * HW + hw0 + lane];
    }
    __syncthreads();
    for (int g = t; g < 512; g += 256) {
        int r = g >> 3, kbl = g & 7;           // granule within 64-ch group
        PK8 h, lo;
        #pragma unroll
        for (int jj = 0; jj < 8; ++jj) {
            float v = ls[kbl * 8 + jj][r];
            ushort hh = bf16_rne(v);
            h.u[jj]  = hh;
            lo.u[jj] = bf16_rne(v - bf16_to_f(hh));
        }
        int kc_l = kbl >> 2, gg = kbl & 3;
        size_t tile = (size_t)mb * 16 + kcc * 2 + kc_l;
        size_t byte = tile * 4096 + (size_t)r * 64 + ((size_t)swz_slot(r, gg) << 4);
        *reinterpret_cast<bf16x8*>(zt_hi + byte) = h.v;
        *reinterpret_cast<bf16x8*>(zt_lo + byte) = lo.v;
    }
}

// ---------------- Main: 64x128 tile, N-split x2, 4 blocks/CU ---------------
// Per step (KC=32): stage A 8KB + B 16KB via gld16, 2 barriers, 24 MFMA/wave.
// TLP (4 blocks/CU, staggered phases) hides the barrier drain (m97 recipe).
__global__ __launch_bounds__(256) void vq_mfma(const char* __restrict__ zt_hi,
                                               const char* __restrict__ zt_lo,
                                               const char* __restrict__ et_hi,
                                               const char* __restrict__ et_lo,
                                               const float* __restrict__ enorm,
                                               float2* __restrict__ cand_b,
                                               int* __restrict__ cand_i) {
    // A hi 4K | A lo 4K | B hi 8K | B lo 8K  = 24KB
    __shared__ __align__(16) char smem[24576];
    __shared__ float red_b1[64][2];
    __shared__ float red_b2[64][2];
    __shared__ int   red_i1[64][2];

    const int t = threadIdx.x;
    const int w = t >> 6, l = t & 63;
    const int lr = l & 15, hg = l >> 4;          // hg = k-granule 0..3
    const int wr = w >> 1;                        // 0..1 -> rows wr*32
    const int wc = w & 1;                         // 0..1 -> cols wc*64
    const int bid = blockIdx.x;
    const int mb = bid >> 1;                      // 0..511 (64-row group)
    const int half = bid & 1;                     // embedding half
    const int n0 = mb * 64;

    const int swz = swz_slot(lr, hg) << 4;        // depends on lr bits 1..2 only
    int aoff[2], boff[4];
    #pragma unroll
    for (int m = 0; m < 2; ++m) aoff[m] = (wr * 32 + m * 16 + lr) * 64 + swz;
    #pragma unroll
    for (int n = 0; n < 4; ++n) boff[n] = (wc * 64 + n * 16 + lr) * 64 + swz;

    float b1v[8], b2v[8]; int i1v[8];
    #pragma unroll
    for (int s = 0; s < 8; ++s) { b1v[s] = FLT_MAX; b2v[s] = FLT_MAX; i1v[s] = 0; }

    const size_t zbase = (size_t)mb * 16 * 4096;
    const int toff = t * 16;

    for (int nci = 0; nci < 4; ++nci) {
        const int nc = half * 4 + nci;
        f32x4 acc[2][4];
        #pragma unroll
        for (int m = 0; m < 2; ++m)
            #pragma unroll
            for (int n = 0; n < 4; ++n) acc[m][n] = (f32x4)(0.f);

        for (int kc = 0; kc < 16; ++kc) {
            __syncthreads();   // prior readers done
            {   // stage A (4K hi + 4K lo), B (8K hi + 8K lo) -- linear gld16
                const char* sAh = zt_hi + zbase + (size_t)kc * 4096;
                const char* sAl = zt_lo + zbase + (size_t)kc * 4096;
                const size_t tB = ((size_t)(nc * 16 + kc)) * 8192;
                gld16(sAh + toff, smem + toff);
                gld16(sAl + toff, smem + 4096 + toff);
                gld16(et_hi + tB + toff,        smem + 8192 + toff);
                gld16(et_hi + tB + 4096 + toff, smem + 12288 + toff);
                gld16(et_lo + tB + toff,        smem + 16384 + toff);
                gld16(et_lo + tB + 4096 + toff, smem + 20480 + toff);
            }
            __syncthreads();   // drain
            bf16x8 ah[2], al[2], bh[4], bl[4];
            #pragma unroll
            for (int m = 0; m < 2; ++m) {
                ah[m] = *reinterpret_cast<const bf16x8*>(smem + aoff[m]);
                al[m] = *reinterpret_cast<const bf16x8*>(smem + 4096 + aoff[m]);
            }
            #pragma unroll
            for (int n = 0; n < 4; ++n) {
                bh[n] = *reinterpret_cast<const bf16x8*>(smem + 8192 + boff[n]);
                bl[n] = *reinterpret_cast<const bf16x8*>(smem + 16384 + boff[n]);
            }
            #pragma unroll
            for (int m = 0; m < 2; ++m)
                #pragma unroll
                for (int n = 0; n < 4; ++n)
                    acc[m][n] = __builtin_amdgcn_mfma_f32_16x16x32_bf16(ah[m], bh[n], acc[m][n], 0, 0, 0);
            #pragma unroll
            for (int m = 0; m < 2; ++m)
                #pragma unroll
                for (int n = 0; n < 4; ++n)
                    acc[m][n] = __builtin_amdgcn_mfma_f32_16x16x32_bf16(ah[m], bl[n], acc[m][n], 0, 0, 0);
            #pragma unroll
            for (int m = 0; m < 2; ++m)
                #pragma unroll
                for (int n = 0; n < 4; ++n)
                    acc[m][n] = __builtin_amdgcn_mfma_f32_16x16x32_bf16(al[m], bh[n], acc[m][n], 0, 0, 0);
        }
        // ---- distances + running best-2 argmin for this nc chunk
        #pragma unroll
        for (int n = 0; n < 4; ++n) {
            const int col = nc * 128 + wc * 64 + n * 16 + lr;
            const float en = enorm[col];
            #pragma unroll
            for (int m = 0; m < 2; ++m) {
                #pragma unroll
                for (int q = 0; q < 4; ++q) {
                    float dv = en - 2.0f * acc[m][n][q];
                    int sl = m * 4 + q;
                    if (dv < b1v[sl]) { b2v[sl] = b1v[sl]; b1v[sl] = dv; i1v[sl] = col; }
                    else if (dv < b2v[sl]) b2v[sl] = dv;
                }
            }
        }
    }

    // ---- butterfly over the 16 col-lanes sharing each row
    #pragma unroll
    for (int s = 0; s < 8; ++s) {
        #pragma unroll
        for (int off = 1; off <= 8; off <<= 1) {
            float ob1 = __shfl_xor(b1v[s], off, 64);
            int   oi1 = __shfl_xor(i1v[s], off, 64);
            float ob2 = __shfl_xor(b2v[s], off, 64);
            if (ob1 < b1v[s] || (ob1 == b1v[s] && oi1 < i1v[s])) {
                b2v[s] = fminf(b1v[s], ob2);
                b1v[s] = ob1; i1v[s] = oi1;
            } else {
                b2v[s] = fminf(b2v[s], ob1);
            }
        }
    }
    __syncthreads();
    if (lr == 0) {
        #pragma unroll
        for (int s = 0; s < 8; ++s) {
            int row = wr * 32 + (s >> 2) * 16 + hg * 4 + (s & 3);
            red_b1[row][wc] = b1v[s];
            red_b2[row][wc] = b2v[s];
            red_i1[row][wc] = i1v[s];
        }
    }
    __syncthreads();
    if (t < 64) {
        float a1 = red_b1[t][0], a2 = red_b2[t][0]; int ai = red_i1[t][0];
        float c1 = red_b1[t][1], c2 = red_b2[t][1]; int ci = red_i1[t][1];
        float B1, B2; int I1;
        if (c1 < a1 || (c1 == a1 && ci < ai)) { B1 = c1; I1 = ci; B2 = fminf(a1, c2); }
        else                                   { B1 = a1; I1 = ai; B2 = fminf(a2, c1); }
        cand_b[(size_t)half * NROW + n0 + t] = make_float2(B1, B2);
        cand_i[(size_t)half * NROW + n0 + t] = I1;
    }
}

// ---------------- Combine: merge halves, write idx, flag, gather -----------
__global__ __launch_bounds__(256) void combine(const float2* __restrict__ cand_b,
                                               const int* __restrict__ cand_i,
                                               const float* __restrict__ e,
                                               float* __restrict__ out,
                                               int* __restrict__ cnt,
                                               int* __restrict__ list) {
    __shared__ int idx_f[64];
    const int t = threadIdx.x;
    const int n0 = blockIdx.x * 64;
    if (t < 64) {
        const int row = n0 + t;
        float2 a = cand_b[row];
        float2 c = cand_b[NROW + row];
        int ai = cand_i[row];
        int ci = cand_i[NROW + row];
        float B1, B2; int I1;
        // half0 indices < half1 indices: strict < keeps lowest-index on ties
        if (c.x < a.x) { B1 = c.x; I1 = ci; B2 = fminf(a.x, c.y); }
        else           { B1 = a.x; I1 = ai; B2 = fminf(a.y, c.x); }
        idx_f[t] = I1;
        out[IOFF + row] = (float)I1;
        if (B2 - B1 < DELTA) {
            int pos = atomicAdd(cnt, 1);
            list[pos] = row;
        }
    }
    if (blockIdx.x == 0 && t == 0) out[SOFF] = 0.0f;
    __syncthreads();

    // gather: out[b][c][hw0+row] = e[idx[row]][c]
    const int b   = n0 >> 10;
    const int hw0 = n0 & (HW - 1);
    const int row4 = (t & 15) * 4;
    const int i0 = idx_f[row4 + 0];
    const int i1 = idx_f[row4 + 1];
    const int i2 = idx_f[row4 + 2];
    const int i3 = idx_f[row4 + 3];
    #pragma unroll 4
    for (int p = 0; p < 32; ++p) {
        int c = (t >> 4) + (p << 4);
        float4 v;
        v.x = e[(size_t)i0 * DIM + c];
        v.y = e[(size_t)i1 * DIM + c];
        v.z = e[(size_t)i2 * DIM + c];
        v.w = e[(size_t)i3 * DIM + c];
        *reinterpret_cast<float4*>(&out[((size_t)(b * DIM + c)) * HW + hw0 + row4]) = v;
    }
}

// ---------------- Recheck: lane-parallel exact fp32 re-scan ----------------
__global__ __launch_bounds__(256) void recheck(const float* __restrict__ z,
                                               const float* __restrict__ e,
                                               const float* __restrict__ enorm,
                                               const int* __restrict__ cnt,
                                               const int* __restrict__ list,
                                               float* __restrict__ out) {
    __shared__ float zrow[512];
    __shared__ float rbest[256];
    __shared__ int   ribi[256];
    __shared__ int   s_fbi;
    const int t = threadIdx.x;
    const int count = *cnt;
    for (int i = blockIdx.x; i < count; i += gridDim.x) {
        const int row = list[i];
        const int b  = row >> 10;
        const int hw = row & (HW - 1);
        __syncthreads();
        zrow[t]       = z[((size_t)(b * DIM + t))       * HW + hw];
        zrow[t + 256] = z[((size_t)(b * DIM + t + 256)) * HW + hw];
        __syncthreads();
        const float4* zr = reinterpret_cast<const float4*>(zrow);
        float best = FLT_MAX; int bi = 0;
        #pragma unroll
        for (int p = 0; p < 4; ++p) {     // ascending ke => strict < keeps lowest index
            const int ke = t + p * 256;
            const float4* ep = reinterpret_cast<const float4*>(e + (size_t)ke * DIM);
            float s0 = 0.f, s1 = 0.f, s2 = 0.f, s3 = 0.f;
            for (int c = 0; c < 128; c += 4) {
                float4 e0 = ep[c],     z0 = zr[c];
                float4 e1 = ep[c + 1], z1 = zr[c + 1];
                float4 e2 = ep[c + 2], z2 = zr[c + 2];
                float4 e3 = ep[c + 3], z3 = zr[c + 3];
                s0 += e0.x*z0.x + e0.y*z0.y + e0.z*z0.z + e0.w*z0.w;
                s1 += e1.x*z1.x + e1.y*z1.y + e1.z*z1.z + e1.w*z1.w;
                s2 += e2.x*z2.x + e2.y*z2.y + e2.z*z2.z + e2.w*z2.w;
                s3 += e3.x*z3.x + e3.y*z3.y + e3.z*z3.z + e3.w*z3.w;
            }
            float dist = enorm[ke] - 2.0f * (((s0 + s1) + (s2 + s3)));
            if (dist < best) { best = dist; bi = ke; }
        }
        rbest[t] = best; ribi[t] = bi;
        __syncthreads();
        #pragma unroll
        for (int s = 128; s > 0; s >>= 1) {
            if (t < s) {
                float ov = rbest[t + s]; int oi = ribi[t + s];
                if (ov < rbest[t] || (ov == rbest[t] && oi < ribi[t])) {
                    rbest[t] = ov; ribi[t] = oi;
                }
            }
            __syncthreads();
        }
        if (t == 0) {
            s_fbi = ribi[0];
            out[IOFF + row] = (float)ribi[0];
        }
        __syncthreads();
        const int fbi = s_fbi;
        out[((size_t)(b * DIM + t))       * HW + hw] = e[(size_t)fbi * DIM + t];
        out[((size_t)(b * DIM + t + 256)) * HW + hw] = e[(size_t)fbi * DIM + t + 256];
    }
}

// ======================= fp32 fallback path (round-2, proven) ================
constexpr int TM = 64;
constexpr int TN = 256;
constexpr int KC = 32;
constexpr int ZST = 68;
constexpr int EST = 260;

union F4 { float4 v; float f[4]; };

__global__ __launch_bounds__(256) void enorm_kernel(const float* __restrict__ e,
                                                    float* __restrict__ enorm) {
    int gid  = blockIdx.x * 256 + threadIdx.x;
    int wave = gid >> 6;
    int lane = gid & 63;
    if (wave >= NEMB) return;
    const float* row = e + (size_t)wave * DIM;
    float4 a = *reinterpret_cast<const float4*>(row + lane * 8);
    float4 b = *reinterpret_cast<const float4*>(row + lane * 8 + 4);
    float s = a.x*a.x + a.y*a.y + a.z*a.z + a.w*a.w
            + b.x*b.x + b.y*b.y + b.z*b.z + b.w*b.w;
    #pragma unroll
    for (int off = 32; off > 0; off >>= 1) s += __shfl_down(s, off, 64);
    if (lane == 0) enorm[wave] = s;
}

__global__ __launch_bounds__(256) void vq_main_kernel(const float* __restrict__ z,
                                                      const float* __restrict__ e,
                                                      const float* __restrict__ enorm,
                                                      float* __restrict__ out) {
    __shared__ float zs[KC][ZST];
    __shared__ float es[KC][EST];
    __shared__ float enorm_l[NEMB];
    __shared__ int   idx_f[TM];

    const int t   = threadIdx.x;
    const int n0  = blockIdx.x * TM;
    const int b   = n0 >> 10;
    const int hw0 = n0 & (HW - 1);
    const float* zb = z + ((size_t)b * DIM) * HW + hw0;

    #pragma unroll
    for (int i = 0; i < 4; ++i) enorm_l[t + i * 256] = enorm[t + i * 256];

    const int rg = t >> 5;
    const int cg = t & 31;

    float best[8];
    int   bidx[8];
    #pragma unroll
    for (int i = 0; i < 8; ++i) { best[i] = FLT_MAX; bidx[i] = 0; }

    const int z_r4 = (t & 15) * 4;
    const int z_c  = t >> 4;
    const int e_ke = t >> 3;
    const int e_c4 = t & 7;

    for (int nc = 0; nc < NEMB / TN; ++nc) {
        const int k0 = nc * TN;
        float acc[8][8];
        #pragma unroll
        for (int mi = 0; mi < 8; ++mi)
            #pragma unroll
            for (int nj = 0; nj < 8; ++nj) acc[mi][nj] = 0.f;

        for (int kc = 0; kc < DIM / KC; ++kc) {
            const int c0 = kc * KC;
            __syncthreads();
            #pragma unroll
            for (int p = 0; p < 2; ++p) {
                int c = z_c + p * 16;
                float4 v = *reinterpret_cast<const float4*>(zb + (size_t)(c0 + c) * HW + z_r4);
                *reinterpret_cast<float4*>(&zs[c][z_r4]) = v;
            }
            #pragma unroll
            for (int p = 0; p < 8; ++p) {
                int ke = e_ke + p * 32;
                float4 v = *reinterpret_cast<const float4*>(e + (size_t)(k0 + ke) * DIM + c0 + e_c4 * 4);
                es[e_c4 * 4 + 0][ke] = v.x;
                es[e_c4 * 4 + 1][ke] = v.y;
                es[e_c4 * 4 + 2][ke] = v.z;
                es[e_c4 * 4 + 3][ke] = v.w;
            }
            __syncthreads();
            #pragma unroll
            for (int kk = 0; kk < KC; ++kk) {
                F4 zf0, zf1, ef0, ef1;
                zf0.v = *reinterpret_cast<const float4*>(&zs[kk][rg * 8]);
                zf1.v = *reinterpret_cast<const float4*>(&zs[kk][rg * 8 + 4]);
                ef0.v = *reinterpret_cast<const float4*>(&es[kk][cg * 4]);
                ef1.v = *reinterpret_cast<const float4*>(&es[kk][128 + cg * 4]);
                #pragma unroll
                for (int mi = 0; mi < 4; ++mi) {
                    #pragma unroll
                    for (int nj = 0; nj < 4; ++nj) {
                        acc[mi][nj]         += zf0.f[mi] * ef0.f[nj];
                        acc[mi][nj + 4]     += zf0.f[mi] * ef1.f[nj];
                        acc[mi + 4][nj]     += zf1.f[mi] * ef0.f[nj];
                        acc[mi + 4][nj + 4] += zf1.f[mi] * ef1.f[nj];
                    }
                }
            }
        }
        #pragma unroll
        for (int mi = 0; mi < 8; ++mi) {
            #pragma unroll
            for (int nj = 0; nj < 8; ++nj) {
                int col = k0 + (nj < 4 ? cg * 4 + nj : 128 + cg * 4 + (nj - 4));
                float dv = enorm_l[col] - 2.0f * acc[mi][nj];
                if (dv < best[mi]) { best[mi] = dv; bidx[mi] = col; }
            }
        }
    }

    __syncthreads();
    float* best_l = reinterpret_cast<float*>(es);
    int*   idx_l  = reinterpret_cast<int*>(reinterpret_cast<char*>(es) + (size_t)TM * 33 * 4);
    #pragma unroll
    for (int mi = 0; mi < 8; ++mi) {
        int row = rg * 8 + mi;
        best_l[row * 33 + cg] = best[mi];
        idx_l[row * 33 + cg]  = bidx[mi];
    }
    __syncthreads();
    if (t < TM) {
        float bv = best_l[t * 33];
        int   bi = idx_l[t * 33];
        #pragma unroll
        for (int c = 1; c < 32; ++c) {
            float v  = best_l[t * 33 + c];
            int   ix = idx_l[t * 33 + c];
            if (v < bv || (v == bv && ix < bi)) { bv = v; bi = ix; }
        }
        idx_f[t] = bi;
        out[IOFF + n0 + t] = (float)bi;
    }
    if (blockIdx.x == 0 && t == 0) out[SOFF] = 0.0f;
    __syncthreads();

    const int row4 = (t & 15) * 4;
    const int i0 = idx_f[row4 + 0];
    const int i1 = idx_f[row4 + 1];
    const int i2 = idx_f[row4 + 2];
    const int i3 = idx_f[row4 + 3];
    #pragma unroll 4
    for (int p = 0; p < 32; ++p) {
        int c = (t >> 4) + (p << 4);
        float4 v;
        v.x = e[(size_t)i0 * DIM + c];
        v.y = e[(size_t)i1 * DIM + c];
        v.z = e[(size_t)i2 * DIM + c];
        v.w = e[(size_t)i3 * DIM + c];
        *reinterpret_cast<float4*>(&out[((size_t)(b * DIM + c)) * HW + hw0 + row4]) = v;
    }
}

// ---------------- host launcher ----------------
extern "C" void kernel_launch(void* const* d_in, const int* in_sizes, int n_in,
                              void* d_out, int out_size, void* d_ws, size_t ws_size,
                              hipStream_t stream) {
    const float* z = (const float*)d_in[0];
    const float* e = (const float*)d_in[1];
    float* out = (float*)d_out;
    char*  ws  = (char*)d_ws;

    if (ws_size >= WS_NEED) {
        char*   zt_hi  = ws + WS_ZHI;
        char*   zt_lo  = ws + WS_ZLO;
        char*   et_hi  = ws + WS_EHI;
        char*   et_lo  = ws + WS_ELO;
        float*  enorm  = (float*)(ws + WS_ENORM);
        int*    cnt    = (int*)(ws + WS_CNT);
        int*    list   = (int*)(ws + WS_LIST);
        float2* cand_b = (float2*)(ws + WS_CANDB);
        int*    cand_i = (int*)(ws + WS_CANDI);

        hipLaunchKernelGGL(enorm_prep, dim3(NEMB / 4), dim3(256), 0, stream, e, enorm, cnt);
        hipLaunchKernelGGL(eprep,      dim3(256),      dim3(256), 0, stream, e, et_hi, et_lo);
        hipLaunchKernelGGL(zprep,      dim3(4096),     dim3(256), 0, stream, z, zt_hi, zt_lo);
        hipLaunchKernelGGL(vq_mfma,    dim3(NROW / 64 * 2), dim3(256), 0, stream,
                           zt_hi, zt_lo, et_hi, et_lo, enorm, cand_b, cand_i);
        hipLaunchKernelGGL(combine,    dim3(NROW / 64), dim3(256), 0, stream,
                           cand_b, cand_i, e, out, cnt, list);
        hipLaunchKernelGGL(recheck,    dim3(256),      dim3(256), 0, stream,
                           z, e, enorm, cnt, list, out);
    } else {
        float* enorm = (float*)ws;
        hipLaunchKernelGGL(enorm_kernel,   dim3(NEMB / 4), dim3(256), 0, stream, e, enorm);
        hipLaunchKernelGGL(vq_main_kernel, dim3(NROW / TM), dim3(256), 0, stream,
                           z, e, enorm, out);
    }
}

// Round 10
// 309.343 us; speedup vs baseline: 1.1470x; 1.1470x over previous
//
#include <hip/hip_runtime.h>
#include <cfloat>

typedef _Float16 half8 __attribute__((ext_vector_type(8)));
typedef float    f32x4 __attribute__((ext_vector_type(4)));
typedef unsigned int  uint;
typedef unsigned short ushort;

// Problem constants
constexpr int DIM  = 512;
constexpr int NEMB = 1024;
constexpr int HW   = 1024;
constexpr int NROW = 32 * HW;   // 32768

constexpr long long QCOUNT = (long long)32 * 512 * 32 * 32; // 16777216
constexpr long long SOFF   = QCOUNT;
constexpr long long IOFF   = SOFF + 1;

// ---------------- ws layout (bytes) ----------------
// zt: 512 mb x 16 kc tiles of (64r x 32k fp16, swizzled) = 4KB -> 32 MB
// et: 8 nc x 16 kc tiles of (128r x 32k fp16, swizzled) = 8KB  -> 1 MB
constexpr size_t WS_ZT    = 0;
constexpr size_t WS_ET    = 33554432;
constexpr size_t WS_ENORM = 34603008;
constexpr size_t WS_CNT   = 34607104;
constexpr size_t WS_LIST  = 34607360;                          // NROW*4
constexpr size_t WS_CANDB = WS_LIST + (size_t)NROW * 4;        // 2*NROW*8
constexpr size_t WS_CANDI = WS_CANDB + (size_t)2 * NROW * 8;   // 2*NROW*4
constexpr size_t WS_NEED  = WS_CANDI + (size_t)2 * NROW * 4;

// fp16 single-pass distance error: realized std ~0.015; DELTA = 0.5 ~ 30 sigma.
constexpr float DELTA = 0.5f;

// ---------------- helpers ----------------
__device__ __forceinline__ void gld16(const void* g, void* l) {
    __builtin_amdgcn_global_load_lds(
        (const __attribute__((address_space(1))) void*)g,
        (__attribute__((address_space(3))) void*)l, 16, 0, 0);
}
union PKH8 { half8 v; _Float16 h[8]; };

// granule swizzle for 64B-row tiles (4 x 16B granules): proven ~0 conflicts (r7-r9)
__device__ __forceinline__ int swz_slot(int r, int g) {
    return g ^ ((r >> 1) & 3);
}

// ---------------- P1: e -> et fp16 tiles + enorm + cnt zero ---------------
__global__ __launch_bounds__(256) void eprep(const float* __restrict__ e,
                                             char* __restrict__ et,
                                             float* __restrict__ enorm,
                                             int* __restrict__ cnt) {
    if (blockIdx.x == 0 && threadIdx.x == 0) *cnt = 0;
    int gid = blockIdx.x * 256 + threadIdx.x;  // 0..65535
    int ke  = gid >> 6;                        // embedding row 0..1023 (wave-aligned)
    int kbg = gid & 63;                        // 16B-granule 0..63 (= lane)
    const float* src = e + (size_t)ke * DIM + kbg * 8;
    PKH8 h;
    float s = 0.f;
    #pragma unroll
    for (int j = 0; j < 8; ++j) {
        float v = src[j];
        h.h[j] = (_Float16)v;   // RNE
        s += v * v;
    }
    int nc = ke >> 7, r = ke & 127, kc = kbg >> 2, g = kbg & 3;
    size_t byte = ((size_t)(nc * 16 + kc)) * 8192 + (size_t)r * 64
                + ((size_t)swz_slot(r, g) << 4);
    *reinterpret_cast<half8*>(et + byte) = h.v;
    // wave reduction of sum-of-squares (64 lanes share one ke)
    #pragma unroll
    for (int off = 32; off > 0; off >>= 1) s += __shfl_down(s, off, 64);
    if (kbg == 0) enorm[ke] = s;
}

// ---------------- P2: z -> zt fp16 swizzled 64x32 tiles (transpose) -------
__global__ __launch_bounds__(256) void zprep(const float* __restrict__ z,
                                             char* __restrict__ zt) {
    __shared__ float ls[64][65];
    const int bx = blockIdx.x;
    const int mb = bx >> 3, kcc = bx & 7;      // kcc: 64-channel group
    const int n0 = mb * 64;
    const int b  = n0 >> 10;
    const int hw0 = n0 & (HW - 1);
    const int t = threadIdx.x;
    const int c4 = t >> 6, lane = t & 63;
    #pragma unroll
    for (int rnd = 0; rnd < 16; ++rnd) {
        int cl = c4 + rnd * 4;
        ls[cl][lane] = z[((size_t)(b * DIM + kcc * 64 + cl)) * HW + hw0 + lane];
    }
    __syncthreads();
    for (int g = t; g < 512; g += 256) {
        int r = g >> 3, kbl = g & 7;           // granule within 64-ch group
        PKH8 h;
        #pragma unroll
        for (int jj = 0; jj < 8; ++jj) h.h[jj] = (_Float16)ls[kbl * 8 + jj][r];
        int kc_l = kbl >> 2, gg = kbl & 3;
        size_t tile = (size_t)mb * 16 + kcc * 2 + kc_l;
        size_t byte = tile * 4096 + (size_t)r * 64 + ((size_t)swz_slot(r, gg) << 4);
        *reinterpret_cast<half8*>(zt + byte) = h.v;
    }
}

// ---------------- Main: fp16 1-pass, 64x128 tile, N-split x2, 4 blk/CU -----
__global__ __launch_bounds__(256) void vq_mfma(const char* __restrict__ zt,
                                               const char* __restrict__ et,
                                               const float* __restrict__ enorm,
                                               float2* __restrict__ cand_b,
                                               int* __restrict__ cand_i) {
    // A 4K | B 8K = 12KB staged per step
    __shared__ __align__(16) char smem[12288];
    __shared__ float red_b1[64][2];
    __shared__ float red_b2[64][2];
    __shared__ int   red_i1[64][2];

    const int t = threadIdx.x;
    const int w = t >> 6, l = t & 63;
    const int lr = l & 15, hg = l >> 4;          // hg = k-granule 0..3
    const int wr = w >> 1;                        // rows wr*32
    const int wc = w & 1;                         // cols wc*64
    const int bid = blockIdx.x;
    const int mb = bid >> 1;                      // 0..511
    const int half = bid & 1;                     // embedding half
    const int n0 = mb * 64;

    const int swz = swz_slot(lr, hg) << 4;
    int aoff[2], boff[4];
    #pragma unroll
    for (int m = 0; m < 2; ++m) aoff[m] = (wr * 32 + m * 16 + lr) * 64 + swz;
    #pragma unroll
    for (int n = 0; n < 4; ++n) boff[n] = (wc * 64 + n * 16 + lr) * 64 + swz;

    float b1v[8], b2v[8]; int i1v[8];
    #pragma unroll
    for (int s = 0; s < 8; ++s) { b1v[s] = FLT_MAX; b2v[s] = FLT_MAX; i1v[s] = 0; }

    const size_t zbase = (size_t)mb * 16 * 4096;
    const int toff = t * 16;

    for (int nci = 0; nci < 4; ++nci) {
        const int nc = half * 4 + nci;
        f32x4 acc[2][4];
        #pragma unroll
        for (int m = 0; m < 2; ++m)
            #pragma unroll
            for (int n = 0; n < 4; ++n) acc[m][n] = (f32x4)(0.f);

        for (int kc = 0; kc < 16; ++kc) {
            __syncthreads();   // prior readers done
            {   // stage A 4KB + B 8KB (3 gld16/thread, linear)
                const size_t tB = ((size_t)(nc * 16 + kc)) * 8192;
                gld16(zt + zbase + (size_t)kc * 4096 + toff, smem + toff);
                gld16(et + tB + toff,        smem + 4096 + toff);
                gld16(et + tB + 4096 + toff, smem + 8192 + toff);
            }
            __syncthreads();   // drain
            half8 ah[2], bh[4];
            #pragma unroll
            for (int m = 0; m < 2; ++m)
                ah[m] = *reinterpret_cast<const half8*>(smem + aoff[m]);
            #pragma unroll
            for (int n = 0; n < 4; ++n)
                bh[n] = *reinterpret_cast<const half8*>(smem + 4096 + boff[n]);
            #pragma unroll
            for (int m = 0; m < 2; ++m)
                #pragma unroll
                for (int n = 0; n < 4; ++n)
                    acc[m][n] = __builtin_amdgcn_mfma_f32_16x16x32_f16(ah[m], bh[n], acc[m][n], 0, 0, 0);
        }
        // ---- distances + running best-2 argmin for this nc chunk
        #pragma unroll
        for (int n = 0; n < 4; ++n) {
            const int col = nc * 128 + wc * 64 + n * 16 + lr;
            const float en = enorm[col];
            #pragma unroll
            for (int m = 0; m < 2; ++m) {
                #pragma unroll
                for (int q = 0; q < 4; ++q) {
                    float dv = en - 2.0f * acc[m][n][q];
                    int sl = m * 4 + q;
                    if (dv < b1v[sl]) { b2v[sl] = b1v[sl]; b1v[sl] = dv; i1v[sl] = col; }
                    else if (dv < b2v[sl]) b2v[sl] = dv;
                }
            }
        }
    }

    // ---- butterfly over the 16 col-lanes sharing each row
    #pragma unroll
    for (int s = 0; s < 8; ++s) {
        #pragma unroll
        for (int off = 1; off <= 8; off <<= 1) {
            float ob1 = __shfl_xor(b1v[s], off, 64);
            int   oi1 = __shfl_xor(i1v[s], off, 64);
            float ob2 = __shfl_xor(b2v[s], off, 64);
            if (ob1 < b1v[s] || (ob1 == b1v[s] && oi1 < i1v[s])) {
                b2v[s] = fminf(b1v[s], ob2);
                b1v[s] = ob1; i1v[s] = oi1;
            } else {
                b2v[s] = fminf(b2v[s], ob1);
            }
        }
    }
    __syncthreads();
    if (lr == 0) {
        #pragma unroll
        for (int s = 0; s < 8; ++s) {
            int row = wr * 32 + (s >> 2) * 16 + hg * 4 + (s & 3);
            red_b1[row][wc] = b1v[s];
            red_b2[row][wc] = b2v[s];
            red_i1[row][wc] = i1v[s];
        }
    }
    __syncthreads();
    if (t < 64) {
        float a1 = red_b1[t][0], a2 = red_b2[t][0]; int ai = red_i1[t][0];
        float c1 = red_b1[t][1], c2 = red_b2[t][1]; int ci = red_i1[t][1];
        float B1, B2; int I1;
        if (c1 < a1 || (c1 == a1 && ci < ai)) { B1 = c1; I1 = ci; B2 = fminf(a1, c2); }
        else                                   { B1 = a1; I1 = ai; B2 = fminf(a2, c1); }
        cand_b[(size_t)half * NROW + n0 + t] = make_float2(B1, B2);
        cand_i[(size_t)half * NROW + n0 + t] = I1;
    }
}

// ---------------- Combine: merge halves, write idx, flag, gather -----------
__global__ __launch_bounds__(256) void combine(const float2* __restrict__ cand_b,
                                               const int* __restrict__ cand_i,
                                               const float* __restrict__ e,
                                               float* __restrict__ out,
                                               int* __restrict__ cnt,
                                               int* __restrict__ list) {
    __shared__ int idx_f[64];
    const int t = threadIdx.x;
    const int n0 = blockIdx.x * 64;
    if (t < 64) {
        const int row = n0 + t;
        float2 a = cand_b[row];
        float2 c = cand_b[NROW + row];
        int ai = cand_i[row];
        int ci = cand_i[NROW + row];
        float B1, B2; int I1;
        // half0 indices < half1 indices: strict < keeps lowest-index on ties
        if (c.x < a.x) { B1 = c.x; I1 = ci; B2 = fminf(a.x, c.y); }
        else           { B1 = a.x; I1 = ai; B2 = fminf(a.y, c.x); }
        idx_f[t] = I1;
        out[IOFF + row] = (float)I1;
        if (B2 - B1 < DELTA) {
            int pos = atomicAdd(cnt, 1);
            list[pos] = row;
        }
    }
    if (blockIdx.x == 0 && t == 0) out[SOFF] = 0.0f;
    __syncthreads();

    // gather: out[b][c][hw0+row] = e[idx[row]][c]
    const int b   = n0 >> 10;
    const int hw0 = n0 & (HW - 1);
    const int row4 = (t & 15) * 4;
    const int i0 = idx_f[row4 + 0];
    const int i1 = idx_f[row4 + 1];
    const int i2 = idx_f[row4 + 2];
    const int i3 = idx_f[row4 + 3];
    #pragma unroll 4
    for (int p = 0; p < 32; ++p) {
        int c = (t >> 4) + (p << 4);
        float4 v;
        v.x = e[(size_t)i0 * DIM + c];
        v.y = e[(size_t)i1 * DIM + c];
        v.z = e[(size_t)i2 * DIM + c];
        v.w = e[(size_t)i3 * DIM + c];
        *reinterpret_cast<float4*>(&out[((size_t)(b * DIM + c)) * HW + hw0 + row4]) = v;
    }
}

// ---------------- Recheck: 4-row-batched exact fp32 re-scan ----------------
// One e-scan (2MB, L2-resident) amortized over up to 4 flagged rows.
__global__ __launch_bounds__(256) void recheck(const float* __restrict__ z,
                                               const float* __restrict__ e,
                                               const float* __restrict__ enorm,
                                               const int* __restrict__ cnt,
                                               const int* __restrict__ list,
                                               float* __restrict__ out) {
    __shared__ float zrow[4][512];
    __shared__ float rb[256];
    __shared__ int   ri[256];
    __shared__ int   fidx[4];
    const int t = threadIdx.x;
    const int count = *cnt;
    const int ngrp = (count + 3) >> 2;
    for (int g = blockIdx.x; g < ngrp; g += gridDim.x) {
        const int base = g * 4;
        const int nr = min(4, count - base);
        __syncthreads();   // guard reuse across group iterations
        for (int r = 0; r < nr; ++r) {
            const int row = list[base + r];
            const int b = row >> 10, hw = row & (HW - 1);
            zrow[r][t]       = z[((size_t)(b * DIM + t))       * HW + hw];
            zrow[r][t + 256] = z[((size_t)(b * DIM + t + 256)) * HW + hw];
        }
        __syncthreads();
        // thread t scans ke = t + 256p (ascending => strict < keeps lowest idx)
        float best[4]; int bi[4];
        #pragma unroll
        for (int r = 0; r < 4; ++r) { best[r] = FLT_MAX; bi[r] = 0; }
        #pragma unroll
        for (int p = 0; p < 4; ++p) {
            const int ke = t + p * 256;
            const float4* ep = reinterpret_cast<const float4*>(e + (size_t)ke * DIM);
            float d0 = 0.f, d1 = 0.f, d2 = 0.f, d3 = 0.f;
            const float4* z0 = reinterpret_cast<const float4*>(zrow[0]);
            const float4* z1 = reinterpret_cast<const float4*>(zrow[1]);
            const float4* z2 = reinterpret_cast<const float4*>(zrow[2]);
            const float4* z3 = reinterpret_cast<const float4*>(zrow[3]);
            for (int c = 0; c < 128; ++c) {
                float4 ev = ep[c];
                float4 a0 = z0[c], a1 = z1[c], a2 = z2[c], a3 = z3[c];
                d0 += ev.x*a0.x + ev.y*a0.y + ev.z*a0.z + ev.w*a0.w;
                d1 += ev.x*a1.x + ev.y*a1.y + ev.z*a1.z + ev.w*a1.w;
                d2 += ev.x*a2.x + ev.y*a2.y + ev.z*a2.z + ev.w*a2.w;
                d3 += ev.x*a3.x + ev.y*a3.y + ev.z*a3.z + ev.w*a3.w;
            }
            const float en = enorm[ke];
            float dd[4] = { en - 2.f*d0, en - 2.f*d1, en - 2.f*d2, en - 2.f*d3 };
            #pragma unroll
            for (int r = 0; r < 4; ++r)
                if (dd[r] < best[r]) { best[r] = dd[r]; bi[r] = ke; }
        }
        // per-row tree reduction (lowest-index tie-break)
        for (int r = 0; r < nr; ++r) {
            rb[t] = best[r]; ri[t] = bi[r];
            __syncthreads();
            #pragma unroll
            for (int s = 128; s > 0; s >>= 1) {
                if (t < s) {
                    float ov = rb[t + s]; int oi = ri[t + s];
                    if (ov < rb[t] || (ov == rb[t] && oi < ri[t])) {
                        rb[t] = ov; ri[t] = oi;
                    }
                }
                __syncthreads();
            }
            if (t == 0) {
                fidx[r] = ri[0];
                out[IOFF + list[base + r]] = (float)ri[0];
            }
            __syncthreads();
        }
        // gather fixed rows
        for (int r = 0; r < nr; ++r) {
            const int row = list[base + r];
            const int b = row >> 10, hw = row & (HW - 1);
            const int fbi = fidx[r];
            out[((size_t)(b * DIM + t))       * HW + hw] = e[(size_t)fbi * DIM + t];
            out[((size_t)(b * DIM + t + 256)) * HW + hw] = e[(size_t)fbi * DIM + t + 256];
        }
    }
}

// ======================= fp32 fallback path (round-2, proven) ================
constexpr int TM = 64;
constexpr int TN = 256;
constexpr int KC = 32;
constexpr int ZST = 68;
constexpr int EST = 260;

union F4 { float4 v; float f[4]; };

__global__ __launch_bounds__(256) void enorm_kernel(const float* __restrict__ e,
                                                    float* __restrict__ enorm) {
    int gid  = blockIdx.x * 256 + threadIdx.x;
    int wave = gid >> 6;
    int lane = gid & 63;
    if (wave >= NEMB) return;
    const float* row = e + (size_t)wave * DIM;
    float4 a = *reinterpret_cast<const float4*>(row + lane * 8);
    float4 b = *reinterpret_cast<const float4*>(row + lane * 8 + 4);
    float s = a.x*a.x + a.y*a.y + a.z*a.z + a.w*a.w
            + b.x*b.x + b.y*b.y + b.z*b.z + b.w*b.w;
    #pragma unroll
    for (int off = 32; off > 0; off >>= 1) s += __shfl_down(s, off, 64);
    if (lane == 0) enorm[wave] = s;
}

__global__ __launch_bounds__(256) void vq_main_kernel(const float* __restrict__ z,
                                                      const float* __restrict__ e,
                                                      const float* __restrict__ enorm,
                                                      float* __restrict__ out) {
    __shared__ float zs[KC][ZST];
    __shared__ float es[KC][EST];
    __shared__ float enorm_l[NEMB];
    __shared__ int   idx_f[TM];

    const int t   = threadIdx.x;
    const int n0  = blockIdx.x * TM;
    const int b   = n0 >> 10;
    const int hw0 = n0 & (HW - 1);
    const float* zb = z + ((size_t)b * DIM) * HW + hw0;

    #pragma unroll
    for (int i = 0; i < 4; ++i) enorm_l[t + i * 256] = enorm[t + i * 256];

    const int rg = t >> 5;
    const int cg = t & 31;

    float best[8];
    int   bidx[8];
    #pragma unroll
    for (int i = 0; i < 8; ++i) { best[i] = FLT_MAX; bidx[i] = 0; }

    const int z_r4 = (t & 15) * 4;
    const int z_c  = t >> 4;
    const int e_ke = t >> 3;
    const int e_c4 = t & 7;

    for (int nc = 0; nc < NEMB / TN; ++nc) {
        const int k0 = nc * TN;
        float acc[8][8];
        #pragma unroll
        for (int mi = 0; mi < 8; ++mi)
            #pragma unroll
            for (int nj = 0; nj < 8; ++nj) acc[mi][nj] = 0.f;

        for (int kc = 0; kc < DIM / KC; ++kc) {
            const int c0 = kc * KC;
            __syncthreads();
            #pragma unroll
            for (int p = 0; p < 2; ++p) {
                int c = z_c + p * 16;
                float4 v = *reinterpret_cast<const float4*>(zb + (size_t)(c0 + c) * HW + z_r4);
                *reinterpret_cast<float4*>(&zs[c][z_r4]) = v;
            }
            #pragma unroll
            for (int p = 0; p < 8; ++p) {
                int ke = e_ke + p * 32;
                float4 v = *reinterpret_cast<const float4*>(e + (size_t)(k0 + ke) * DIM + c0 + e_c4 * 4);
                es[e_c4 * 4 + 0][ke] = v.x;
                es[e_c4 * 4 + 1][ke] = v.y;
                es[e_c4 * 4 + 2][ke] = v.z;
                es[e_c4 * 4 + 3][ke] = v.w;
            }
            __syncthreads();
            #pragma unroll
            for (int kk = 0; kk < KC; ++kk) {
                F4 zf0, zf1, ef0, ef1;
                zf0.v = *reinterpret_cast<const float4*>(&zs[kk][rg * 8]);
                zf1.v = *reinterpret_cast<const float4*>(&zs[kk][rg * 8 + 4]);
                ef0.v = *reinterpret_cast<const float4*>(&es[kk][cg * 4]);
                ef1.v = *reinterpret_cast<const float4*>(&es[kk][128 + cg * 4]);
                #pragma unroll
                for (int mi = 0; mi < 4; ++mi) {
                    #pragma unroll
                    for (int nj = 0; nj < 4; ++nj) {
                        acc[mi][nj]         += zf0.f[mi] * ef0.f[nj];
                        acc[mi][nj + 4]     += zf0.f[mi] * ef1.f[nj];
                        acc[mi + 4][nj]     += zf1.f[mi] * ef0.f[nj];
                        acc[mi + 4][nj + 4] += zf1.f[mi] * ef1.f[nj];
                    }
                }
            }
        }
        #pragma unroll
        for (int mi = 0; mi < 8; ++mi) {
            #pragma unroll
            for (int nj = 0; nj < 8; ++nj) {
                int col = k0 + (nj < 4 ? cg * 4 + nj : 128 + cg * 4 + (nj - 4));
                float dv = enorm_l[col] - 2.0f * acc[mi][nj];
                if (dv < best[mi]) { best[mi] = dv; bidx[mi] = col; }
            }
        }
    }

    __syncthreads();
    float* best_l = reinterpret_cast<float*>(es);
    int*   idx_l  = reinterpret_cast<int*>(reinterpret_cast<char*>(es) + (size_t)TM * 33 * 4);
    #pragma unroll
    for (int mi = 0; mi < 8; ++mi) {
        int row = rg * 8 + mi;
        best_l[row * 33 + cg] = best[mi];
        idx_l[row * 33 + cg]  = bidx[mi];
    }
    __syncthreads();
    if (t < TM) {
        float bv = best_l[t * 33];
        int   bi = idx_l[t * 33];
        #pragma unroll
        for (int c = 1; c < 32; ++c) {
            float v  = best_l[t * 33 + c];
            int   ix = idx_l[t * 33 + c];
            if (v < bv || (v == bv && ix < bi)) { bv = v; bi = ix; }
        }
        idx_f[t] = bi;
        out[IOFF + n0 + t] = (float)bi;
    }
    if (blockIdx.x == 0 && t == 0) out[SOFF] = 0.0f;
    __syncthreads();

    const int row4 = (t & 15) * 4;
    const int i0 = idx_f[row4 + 0];
    const int i1 = idx_f[row4 + 1];
    const int i2 = idx_f[row4 + 2];
    const int i3 = idx_f[row4 + 3];
    #pragma unroll 4
    for (int p = 0; p < 32; ++p) {
        int c = (t >> 4) + (p << 4);
        float4 v;
        v.x = e[(size_t)i0 * DIM + c];
        v.y = e[(size_t)i1 * DIM + c];
        v.z = e[(size_t)i2 * DIM + c];
        v.w = e[(size_t)i3 * DIM + c];
        *reinterpret_cast<float4*>(&out[((size_t)(b * DIM + c)) * HW + hw0 + row4]) = v;
    }
}

// ---------------- host launcher ----------------
extern "C" void kernel_launch(void* const* d_in, const int* in_sizes, int n_in,
                              void* d_out, int out_size, void* d_ws, size_t ws_size,
                              hipStream_t stream) {
    const float* z = (const float*)d_in[0];
    const float* e = (const float*)d_in[1];
    float* out = (float*)d_out;
    char*  ws  = (char*)d_ws;

    if (ws_size >= WS_NEED) {
        char*   zt     = ws + WS_ZT;
        char*   et     = ws + WS_ET;
        float*  enorm  = (float*)(ws + WS_ENORM);
        int*    cnt    = (int*)(ws + WS_CNT);
        int*    list   = (int*)(ws + WS_LIST);
        float2* cand_b = (float2*)(ws + WS_CANDB);
        int*    cand_i = (int*)(ws + WS_CANDI);

        hipLaunchKernelGGL(eprep,   dim3(256),           dim3(256), 0, stream, e, et, enorm, cnt);
        hipLaunchKernelGGL(zprep,   dim3(4096),          dim3(256), 0, stream, z, zt);
        hipLaunchKernelGGL(vq_mfma, dim3(NROW / 64 * 2), dim3(256), 0, stream,
                           zt, et, enorm, cand_b, cand_i);
        hipLaunchKernelGGL(combine, dim3(NROW / 64),     dim3(256), 0, stream,
                           cand_b, cand_i, e, out, cnt, list);
        hipLaunchKernelGGL(recheck, dim3(256),           dim3(256), 0, stream,
                           z, e, enorm, cnt, list, out);
    } else {
        float* enorm = (float*)ws;
        hipLaunchKernelGGL(enorm_kernel,   dim3(NEMB / 4), dim3(256), 0, stream, e, enorm);
        hipLaunchKernelGGL(vq_main_kernel, dim3(NROW / TM), dim3(256), 0, stream,
                           z, e, enorm, out);
    }
}

// Round 11
// 288.275 us; speedup vs baseline: 1.2308x; 1.0731x over previous
//
#include <hip/hip_runtime.h>
#include <cfloat>

typedef _Float16 half8 __attribute__((ext_vector_type(8)));
typedef float    f32x4 __attribute__((ext_vector_type(4)));
typedef unsigned int  uint;
typedef unsigned short ushort;

// Problem constants
constexpr int DIM  = 512;
constexpr int NEMB = 1024;
constexpr int HW   = 1024;
constexpr int NROW = 32 * HW;   // 32768

constexpr long long QCOUNT = (long long)32 * 512 * 32 * 32; // 16777216
constexpr long long SOFF   = QCOUNT;
constexpr long long IOFF   = SOFF + 1;

// ---------------- ws layout (bytes) ----------------
constexpr size_t WS_ZT    = 0;
constexpr size_t WS_ET    = 33554432;
constexpr size_t WS_ENORM = 34603008;
constexpr size_t WS_CNT   = 34607104;
constexpr size_t WS_LIST  = 34607360;                          // NROW*4
constexpr size_t WS_CANDB = WS_LIST + (size_t)NROW * 4;        // 2*NROW*8
constexpr size_t WS_CANDI = WS_CANDB + (size_t)2 * NROW * 8;   // 2*NROW*4
constexpr size_t WS_NEED  = WS_CANDI + (size_t)2 * NROW * 4;

// fp16 single-pass distance error: realized std ~0.015; DELTA = 0.5 ~ 30 sigma.
constexpr float DELTA = 0.5f;

// ---------------- helpers ----------------
__device__ __forceinline__ void gld16(const void* g, void* l) {
    __builtin_amdgcn_global_load_lds(
        (const __attribute__((address_space(1))) void*)g,
        (__attribute__((address_space(3))) void*)l, 16, 0, 0);
}
union PKH8 { half8 v; _Float16 h[8]; };

// granule swizzle for 64B-row tiles (4 x 16B granules): proven ~0 conflicts (r7-r10)
__device__ __forceinline__ int swz_slot(int r, int g) {
    return g ^ ((r >> 1) & 3);
}

// ---------------- P1: e -> et fp16 tiles + enorm + cnt zero ---------------
__global__ __launch_bounds__(256) void eprep(const float* __restrict__ e,
                                             char* __restrict__ et,
                                             float* __restrict__ enorm,
                                             int* __restrict__ cnt) {
    if (blockIdx.x == 0 && threadIdx.x == 0) *cnt = 0;
    int gid = blockIdx.x * 256 + threadIdx.x;  // 0..65535
    int ke  = gid >> 6;                        // embedding row (wave-aligned)
    int kbg = gid & 63;                        // 16B-granule (= lane)
    const float* src = e + (size_t)ke * DIM + kbg * 8;
    PKH8 h;
    float s = 0.f;
    #pragma unroll
    for (int j = 0; j < 8; ++j) {
        float v = src[j];
        h.h[j] = (_Float16)v;   // RNE
        s += v * v;
    }
    int nc = ke >> 7, r = ke & 127, kc = kbg >> 2, g = kbg & 3;
    size_t byte = ((size_t)(nc * 16 + kc)) * 8192 + (size_t)r * 64
                + ((size_t)swz_slot(r, g) << 4);
    *reinterpret_cast<half8*>(et + byte) = h.v;
    #pragma unroll
    for (int off = 32; off > 0; off >>= 1) s += __shfl_down(s, off, 64);
    if (kbg == 0) enorm[ke] = s;
}

// ---------------- P2: z -> zt fp16 swizzled 64x32 tiles (transpose) -------
__global__ __launch_bounds__(256) void zprep(const float* __restrict__ z,
                                             char* __restrict__ zt) {
    __shared__ float ls[64][65];
    const int bx = blockIdx.x;
    const int mb = bx >> 3, kcc = bx & 7;      // kcc: 64-channel group
    const int n0 = mb * 64;
    const int b  = n0 >> 10;
    const int hw0 = n0 & (HW - 1);
    const int t = threadIdx.x;
    const int c4 = t >> 6, lane = t & 63;
    #pragma unroll
    for (int rnd = 0; rnd < 16; ++rnd) {
        int cl = c4 + rnd * 4;
        ls[cl][lane] = z[((size_t)(b * DIM + kcc * 64 + cl)) * HW + hw0 + lane];
    }
    __syncthreads();
    for (int g = t; g < 512; g += 256) {
        int r = g >> 3, kbl = g & 7;
        PKH8 h;
        #pragma unroll
        for (int jj = 0; jj < 8; ++jj) h.h[jj] = (_Float16)ls[kbl * 8 + jj][r];
        int kc_l = kbl >> 2, gg = kbl & 3;
        size_t tile = (size_t)mb * 16 + kcc * 2 + kc_l;
        size_t byte = tile * 4096 + (size_t)r * 64 + ((size_t)swz_slot(r, gg) << 4);
        *reinterpret_cast<half8*>(zt + byte) = h.v;
    }
}

// ---------------- Main: counted-vmcnt depth-3 pipeline (T3/T4) -------------
// Per step: vmcnt(6) [oldest stage done] -> s_barrier -> ds_read frags ->
// lgkmcnt(0)+sched_barrier -> s_barrier -> issue stage s+3 -> 8 MFMA.
// VMEM latency spans 3 steps of compute; vmcnt never drains to 0 in-loop.
#define VQ_STAGE(SS)                                                           \
  {                                                                            \
    const int kc_ = (SS) & 15;                                                 \
    const size_t tB_ = ((size_t)((half * 4 + ((SS) >> 4)) * 16 + kc_)) * 8192; \
    char* dst_ = smem + ((SS) % 3) * 12288;                                    \
    gld16(zt + zbase + (size_t)kc_ * 4096 + toff, dst_ + toff);                \
    gld16(et + tB_ + toff,        dst_ + 4096 + toff);                         \
    gld16(et + tB_ + 4096 + toff, dst_ + 8192 + toff);                         \
  }

#define VQ_STEP(S, VMLIT)                                                      \
  {                                                                            \
    asm volatile("s_waitcnt vmcnt(" VMLIT ")" ::: "memory");                   \
    __builtin_amdgcn_s_barrier();                                              \
    const char* buf_ = smem + ((S) % 3) * 12288;                               \
    half8 ah0 = *reinterpret_cast<const half8*>(buf_ + aoff0);                 \
    half8 ah1 = *reinterpret_cast<const half8*>(buf_ + aoff1);                 \
    half8 bh0 = *reinterpret_cast<const half8*>(buf_ + 4096 + boff0);          \
    half8 bh1 = *reinterpret_cast<const half8*>(buf_ + 4096 + boff1);          \
    half8 bh2 = *reinterpret_cast<const half8*>(buf_ + 4096 + boff2);          \
    half8 bh3 = *reinterpret_cast<const half8*>(buf_ + 4096 + boff3);          \
    asm volatile("s_waitcnt lgkmcnt(0)" ::: "memory");                         \
    __builtin_amdgcn_sched_barrier(0);                                         \
    __builtin_amdgcn_s_barrier();                                              \
    if ((S) + 3 < 64) VQ_STAGE((S) + 3);                                       \
    acc[0][0] = __builtin_amdgcn_mfma_f32_16x16x32_f16(ah0, bh0, acc[0][0], 0, 0, 0); \
    acc[0][1] = __builtin_amdgcn_mfma_f32_16x16x32_f16(ah0, bh1, acc[0][1], 0, 0, 0); \
    acc[0][2] = __builtin_amdgcn_mfma_f32_16x16x32_f16(ah0, bh2, acc[0][2], 0, 0, 0); \
    acc[0][3] = __builtin_amdgcn_mfma_f32_16x16x32_f16(ah0, bh3, acc[0][3], 0, 0, 0); \
    acc[1][0] = __builtin_amdgcn_mfma_f32_16x16x32_f16(ah1, bh0, acc[1][0], 0, 0, 0); \
    acc[1][1] = __builtin_amdgcn_mfma_f32_16x16x32_f16(ah1, bh1, acc[1][1], 0, 0, 0); \
    acc[1][2] = __builtin_amdgcn_mfma_f32_16x16x32_f16(ah1, bh2, acc[1][2], 0, 0, 0); \
    acc[1][3] = __builtin_amdgcn_mfma_f32_16x16x32_f16(ah1, bh3, acc[1][3], 0, 0, 0); \
    if (((S) & 15) == 15) {                                                    \
      const int ncl_ = ((S) >> 4) * 128;                                       \
      _Pragma("unroll")                                                        \
      for (int n = 0; n < 4; ++n) {                                            \
        const int lcol = ncl_ + wc * 64 + n * 16 + lr;                         \
        const float en = enorm_l[lcol];                                        \
        const int col = half * 512 + lcol;                                     \
        _Pragma("unroll")                                                      \
        for (int m = 0; m < 2; ++m) {                                          \
          _Pragma("unroll")                                                    \
          for (int q = 0; q < 4; ++q) {                                        \
            float dv = en - 2.0f * acc[m][n][q];                               \
            int sl = m * 4 + q;                                                \
            if (dv < b1v[sl]) { b2v[sl] = b1v[sl]; b1v[sl] = dv; i1v[sl] = col; } \
            else if (dv < b2v[sl]) b2v[sl] = dv;                               \
          }                                                                    \
        }                                                                      \
      }                                                                        \
      _Pragma("unroll")                                                        \
      for (int m = 0; m < 2; ++m)                                              \
        _Pragma("unroll")                                                      \
        for (int n = 0; n < 4; ++n) acc[m][n] = (f32x4)(0.f);                  \
    }                                                                          \
  }

__global__ __launch_bounds__(256, 4) void vq_mfma(const char* __restrict__ zt,
                                                  const char* __restrict__ et,
                                                  const float* __restrict__ enorm,
                                                  float2* __restrict__ cand_b,
                                                  int* __restrict__ cand_i) {
    __shared__ __align__(16) char smem[36864];   // 3 x 12KB stage ring
    __shared__ float enorm_l[512];

    const int t = threadIdx.x;
    const int w = t >> 6, l = t & 63;
    const int lr = l & 15, hg = l >> 4;          // hg = k-granule 0..3
    const int wr = w >> 1;                        // rows wr*32
    const int wc = w & 1;                         // cols wc*64
    const int bid = blockIdx.x;
    const int mb = bid >> 1;                      // 0..511
    const int half = bid & 1;                     // embedding half
    const int n0 = mb * 64;

    const int swz = swz_slot(lr, hg) << 4;
    const int aoff0 = (wr * 32 + lr) * 64 + swz;
    const int aoff1 = (wr * 32 + 16 + lr) * 64 + swz;
    const int boff0 = (wc * 64 + lr) * 64 + swz;
    const int boff1 = (wc * 64 + 16 + lr) * 64 + swz;
    const int boff2 = (wc * 64 + 32 + lr) * 64 + swz;
    const int boff3 = (wc * 64 + 48 + lr) * 64 + swz;

    // stage this half's enorm to LDS (keeps in-loop VMEM = gld16 only,
    // so the counted vmcnt stays exact)
    enorm_l[t]       = enorm[half * 512 + t];
    enorm_l[t + 256] = enorm[half * 512 + t + 256];
    __syncthreads();

    float b1v[8], b2v[8]; int i1v[8];
    #pragma unroll
    for (int s = 0; s < 8; ++s) { b1v[s] = FLT_MAX; b2v[s] = FLT_MAX; i1v[s] = 0; }

    const size_t zbase = (size_t)mb * 16 * 4096;
    const int toff = t * 16;

    f32x4 acc[2][4];
    #pragma unroll
    for (int m = 0; m < 2; ++m)
        #pragma unroll
        for (int n = 0; n < 4; ++n) acc[m][n] = (f32x4)(0.f);

    // prologue: issue stages 0..2 (9 VMEM instrs in flight)
    VQ_STAGE(0);
    VQ_STAGE(1);
    VQ_STAGE(2);

    for (int s = 0; s < 62; ++s) {
        VQ_STEP(s, "6");
    }
    VQ_STEP(62, "3");
    VQ_STEP(63, "0");

    // ---- butterfly over the 16 col-lanes sharing each row
    #pragma unroll
    for (int s = 0; s < 8; ++s) {
        #pragma unroll
        for (int off = 1; off <= 8; off <<= 1) {
            float ob1 = __shfl_xor(b1v[s], off, 64);
            int   oi1 = __shfl_xor(i1v[s], off, 64);
            float ob2 = __shfl_xor(b2v[s], off, 64);
            if (ob1 < b1v[s] || (ob1 == b1v[s] && oi1 < i1v[s])) {
                b2v[s] = fminf(b1v[s], ob2);
                b1v[s] = ob1; i1v[s] = oi1;
            } else {
                b2v[s] = fminf(b2v[s], ob1);
            }
        }
    }
    // ---- block reduction across the 2 col-waves (overlay on dead stage ring)
    __syncthreads();
    float* red_b1 = reinterpret_cast<float*>(smem);          // [64][2]
    float* red_b2 = reinterpret_cast<float*>(smem + 512);    // [64][2]
    int*   red_i1 = reinterpret_cast<int*>  (smem + 1024);   // [64][2]
    if (lr == 0) {
        #pragma unroll
        for (int s = 0; s < 8; ++s) {
            int row = wr * 32 + (s >> 2) * 16 + hg * 4 + (s & 3);
            red_b1[row * 2 + wc] = b1v[s];
            red_b2[row * 2 + wc] = b2v[s];
            red_i1[row * 2 + wc] = i1v[s];
        }
    }
    __syncthreads();
    if (t < 64) {
        float a1 = red_b1[t * 2], a2 = red_b2[t * 2]; int ai = red_i1[t * 2];
        float c1 = red_b1[t * 2 + 1], c2 = red_b2[t * 2 + 1]; int ci = red_i1[t * 2 + 1];
        float B1, B2; int I1;
        if (c1 < a1 || (c1 == a1 && ci < ai)) { B1 = c1; I1 = ci; B2 = fminf(a1, c2); }
        else                                   { B1 = a1; I1 = ai; B2 = fminf(a2, c1); }
        cand_b[(size_t)half * NROW + n0 + t] = make_float2(B1, B2);
        cand_i[(size_t)half * NROW + n0 + t] = I1;
    }
}

// ---------------- Combine: merge halves, write idx, flag, gather -----------
__global__ __launch_bounds__(256) void combine(const float2* __restrict__ cand_b,
                                               const int* __restrict__ cand_i,
                                               const float* __restrict__ e,
                                               float* __restrict__ out,
                                               int* __restrict__ cnt,
                                               int* __restrict__ list) {
    __shared__ int idx_f[64];
    const int t = threadIdx.x;
    const int n0 = blockIdx.x * 64;
    if (t < 64) {
        const int row = n0 + t;
        float2 a = cand_b[row];
        float2 c = cand_b[NROW + row];
        int ai = cand_i[row];
        int ci = cand_i[NROW + row];
        float B1, B2; int I1;
        // half0 indices < half1 indices: strict < keeps lowest-index on ties
        if (c.x < a.x) { B1 = c.x; I1 = ci; B2 = fminf(a.x, c.y); }
        else           { B1 = a.x; I1 = ai; B2 = fminf(a.y, c.x); }
        idx_f[t] = I1;
        out[IOFF + row] = (float)I1;
        if (B2 - B1 < DELTA) {
            int pos = atomicAdd(cnt, 1);
            list[pos] = row;
        }
    }
    if (blockIdx.x == 0 && t == 0) out[SOFF] = 0.0f;
    __syncthreads();

    // gather: out[b][c][hw0+row] = e[idx[row]][c]
    const int b   = n0 >> 10;
    const int hw0 = n0 & (HW - 1);
    const int row4 = (t & 15) * 4;
    const int i0 = idx_f[row4 + 0];
    const int i1 = idx_f[row4 + 1];
    const int i2 = idx_f[row4 + 2];
    const int i3 = idx_f[row4 + 3];
    #pragma unroll 4
    for (int p = 0; p < 32; ++p) {
        int c = (t >> 4) + (p << 4);
        float4 v;
        v.x = e[(size_t)i0 * DIM + c];
        v.y = e[(size_t)i1 * DIM + c];
        v.z = e[(size_t)i2 * DIM + c];
        v.w = e[(size_t)i3 * DIM + c];
        *reinterpret_cast<float4*>(&out[((size_t)(b * DIM + c)) * HW + hw0 + row4]) = v;
    }
}

// ---------------- Recheck: 4-row-batched exact fp32 re-scan ----------------
__global__ __launch_bounds__(256) void recheck(const float* __restrict__ z,
                                               const float* __restrict__ e,
                                               const float* __restrict__ enorm,
                                               const int* __restrict__ cnt,
                                               const int* __restrict__ list,
                                               float* __restrict__ out) {
    __shared__ float zrow[4][512];
    __shared__ float rb[256];
    __shared__ int   ri[256];
    __shared__ int   fidx[4];
    const int t = threadIdx.x;
    const int count = *cnt;
    const int ngrp = (count + 3) >> 2;
    for (int g = blockIdx.x; g < ngrp; g += gridDim.x) {
        const int base = g * 4;
        const int nr = min(4, count - base);
        __syncthreads();
        for (int r = 0; r < nr; ++r) {
            const int row = list[base + r];
            const int b = row >> 10, hw = row & (HW - 1);
            zrow[r][t]       = z[((size_t)(b * DIM + t))       * HW + hw];
            zrow[r][t + 256] = z[((size_t)(b * DIM + t + 256)) * HW + hw];
        }
        __syncthreads();
        float best[4]; int bi[4];
        #pragma unroll
        for (int r = 0; r < 4; ++r) { best[r] = FLT_MAX; bi[r] = 0; }
        #pragma unroll
        for (int p = 0; p < 4; ++p) {
            const int ke = t + p * 256;
            const float4* ep = reinterpret_cast<const float4*>(e + (size_t)ke * DIM);
            float d0 = 0.f, d1 = 0.f, d2 = 0.f, d3 = 0.f;
            const float4* z0 = reinterpret_cast<const float4*>(zrow[0]);
            const float4* z1 = reinterpret_cast<const float4*>(zrow[1]);
            const float4* z2 = reinterpret_cast<const float4*>(zrow[2]);
            const float4* z3 = reinterpret_cast<const float4*>(zrow[3]);
            for (int c = 0; c < 128; ++c) {
                float4 ev = ep[c];
                float4 a0 = z0[c], a1 = z1[c], a2 = z2[c], a3 = z3[c];
                d0 += ev.x*a0.x + ev.y*a0.y + ev.z*a0.z + ev.w*a0.w;
                d1 += ev.x*a1.x + ev.y*a1.y + ev.z*a1.z + ev.w*a1.w;
                d2 += ev.x*a2.x + ev.y*a2.y + ev.z*a2.z + ev.w*a2.w;
                d3 += ev.x*a3.x + ev.y*a3.y + ev.z*a3.z + ev.w*a3.w;
            }
            const float en = enorm[ke];
            float dd[4] = { en - 2.f*d0, en - 2.f*d1, en - 2.f*d2, en - 2.f*d3 };
            #pragma unroll
            for (int r = 0; r < 4; ++r)
                if (dd[r] < best[r]) { best[r] = dd[r]; bi[r] = ke; }
        }
        for (int r = 0; r < nr; ++r) {
            rb[t] = best[r]; ri[t] = bi[r];
            __syncthreads();
            #pragma unroll
            for (int s = 128; s > 0; s >>= 1) {
                if (t < s) {
                    float ov = rb[t + s]; int oi = ri[t + s];
                    if (ov < rb[t] || (ov == rb[t] && oi < ri[t])) {
                        rb[t] = ov; ri[t] = oi;
                    }
                }
                __syncthreads();
            }
            if (t == 0) {
                fidx[r] = ri[0];
                out[IOFF + list[base + r]] = (float)ri[0];
            }
            __syncthreads();
        }
        for (int r = 0; r < nr; ++r) {
            const int row = list[base + r];
            const int b = row >> 10, hw = row & (HW - 1);
            const int fbi = fidx[r];
            out[((size_t)(b * DIM + t))       * HW + hw] = e[(size_t)fbi * DIM + t];
            out[((size_t)(b * DIM + t + 256)) * HW + hw] = e[(size_t)fbi * DIM + t + 256];
        }
    }
}

// ======================= fp32 fallback path (round-2, proven) ================
constexpr int TM = 64;
constexpr int TN = 256;
constexpr int KC = 32;
constexpr int ZST = 68;
constexpr int EST = 260;

union F4 { float4 v; float f[4]; };

__global__ __launch_bounds__(256) void enorm_kernel(const float* __restrict__ e,
                                                    float* __restrict__ enorm) {
    int gid  = blockIdx.x * 256 + threadIdx.x;
    int wave = gid >> 6;
    int lane = gid & 63;
    if (wave >= NEMB) return;
    const float* row = e + (size_t)wave * DIM;
    float4 a = *reinterpret_cast<const float4*>(row + lane * 8);
    float4 b = *reinterpret_cast<const float4*>(row + lane * 8 + 4);
    float s = a.x*a.x + a.y*a.y + a.z*a.z + a.w*a.w
            + b.x*b.x + b.y*b.y + b.z*b.z + b.w*b.w;
    #pragma unroll
    for (int off = 32; off > 0; off >>= 1) s += __shfl_down(s, off, 64);
    if (lane == 0) enorm[wave] = s;
}

__global__ __launch_bounds__(256) void vq_main_kernel(const float* __restrict__ z,
                                                      const float* __restrict__ e,
                                                      const float* __restrict__ enorm,
                                                      float* __restrict__ out) {
    __shared__ float zs[KC][ZST];
    __shared__ float es[KC][EST];
    __shared__ float enorm_l[NEMB];
    __shared__ int   idx_f[TM];

    const int t   = threadIdx.x;
    const int n0  = blockIdx.x * TM;
    const int b   = n0 >> 10;
    const int hw0 = n0 & (HW - 1);
    const float* zb = z + ((size_t)b * DIM) * HW + hw0;

    #pragma unroll
    for (int i = 0; i < 4; ++i) enorm_l[t + i * 256] = enorm[t + i * 256];

    const int rg = t >> 5;
    const int cg = t & 31;

    float best[8];
    int   bidx[8];
    #pragma unroll
    for (int i = 0; i < 8; ++i) { best[i] = FLT_MAX; bidx[i] = 0; }

    const int z_r4 = (t & 15) * 4;
    const int z_c  = t >> 4;
    const int e_ke = t >> 3;
    const int e_c4 = t & 7;

    for (int nc = 0; nc < NEMB / TN; ++nc) {
        const int k0 = nc * TN;
        float acc[8][8];
        #pragma unroll
        for (int mi = 0; mi < 8; ++mi)
            #pragma unroll
            for (int nj = 0; nj < 8; ++nj) acc[mi][nj] = 0.f;

        for (int kc = 0; kc < DIM / KC; ++kc) {
            const int c0 = kc * KC;
            __syncthreads();
            #pragma unroll
            for (int p = 0; p < 2; ++p) {
                int c = z_c + p * 16;
                float4 v = *reinterpret_cast<const float4*>(zb + (size_t)(c0 + c) * HW + z_r4);
                *reinterpret_cast<float4*>(&zs[c][z_r4]) = v;
            }
            #pragma unroll
            for (int p = 0; p < 8; ++p) {
                int ke = e_ke + p * 32;
                float4 v = *reinterpret_cast<const float4*>(e + (size_t)(k0 + ke) * DIM + c0 + e_c4 * 4);
                es[e_c4 * 4 + 0][ke] = v.x;
                es[e_c4 * 4 + 1][ke] = v.y;
                es[e_c4 * 4 + 2][ke] = v.z;
                es[e_c4 * 4 + 3][ke] = v.w;
            }
            __syncthreads();
            #pragma unroll
            for (int kk = 0; kk < KC; ++kk) {
                F4 zf0, zf1, ef0, ef1;
                zf0.v = *reinterpret_cast<const float4*>(&zs[kk][rg * 8]);
                zf1.v = *reinterpret_cast<const float4*>(&zs[kk][rg * 8 + 4]);
                ef0.v = *reinterpret_cast<const float4*>(&es[kk][cg * 4]);
                ef1.v = *reinterpret_cast<const float4*>(&es[kk][128 + cg * 4]);
                #pragma unroll
                for (int mi = 0; mi < 4; ++mi) {
                    #pragma unroll
                    for (int nj = 0; nj < 4; ++nj) {
                        acc[mi][nj]         += zf0.f[mi] * ef0.f[nj];
                        acc[mi][nj + 4]     += zf0.f[mi] * ef1.f[nj];
                        acc[mi + 4][nj]     += zf1.f[mi] * ef0.f[nj];
                        acc[mi + 4][nj + 4] += zf1.f[mi] * ef1.f[nj];
                    }
                }
            }
        }
        #pragma unroll
        for (int mi = 0; mi < 8; ++mi) {
            #pragma unroll
            for (int nj = 0; nj < 8; ++nj) {
                int col = k0 + (nj < 4 ? cg * 4 + nj : 128 + cg * 4 + (nj - 4));
                float dv = enorm_l[col] - 2.0f * acc[mi][nj];
                if (dv < best[mi]) { best[mi] = dv; bidx[mi] = col; }
            }
        }
    }

    __syncthreads();
    float* best_l = reinterpret_cast<float*>(es);
    int*   idx_l  = reinterpret_cast<int*>(reinterpret_cast<char*>(es) + (size_t)TM * 33 * 4);
    #pragma unroll
    for (int mi = 0; mi < 8; ++mi) {
        int row = rg * 8 + mi;
        best_l[row * 33 + cg] = best[mi];
        idx_l[row * 33 + cg]  = bidx[mi];
    }
    __syncthreads();
    if (t < TM) {
        float bv = best_l[t * 33];
        int   bi = idx_l[t * 33];
        #pragma unroll
        for (int c = 1; c < 32; ++c) {
            float v  = best_l[t * 33 + c];
            int   ix = idx_l[t * 33 + c];
            if (v < bv || (v == bv && ix < bi)) { bv = v; bi = ix; }
        }
        idx_f[t] = bi;
        out[IOFF + n0 + t] = (float)bi;
    }
    if (blockIdx.x == 0 && t == 0) out[SOFF] = 0.0f;
    __syncthreads();

    const int row4 = (t & 15) * 4;
    const int i0 = idx_f[row4 + 0];
    const int i1 = idx_f[row4 + 1];
    const int i2 = idx_f[row4 + 2];
    const int i3 = idx_f[row4 + 3];
    #pragma unroll 4
    for (int p = 0; p < 32; ++p) {
        int c = (t >> 4) + (p << 4);
        float4 v;
        v.x = e[(size_t)i0 * DIM + c];
        v.y = e[(size_t)i1 * DIM + c];
        v.z = e[(size_t)i2 * DIM + c];
        v.w = e[(size_t)i3 * DIM + c];
        *reinterpret_cast<float4*>(&out[((size_t)(b * DIM + c)) * HW + hw0 + row4]) = v;
    }
}

// ---------------- host launcher ----------------
extern "C" void kernel_launch(void* const* d_in, const int* in_sizes, int n_in,
                              void* d_out, int out_size, void* d_ws, size_t ws_size,
                              hipStream_t stream) {
    const float* z = (const float*)d_in[0];
    const float* e = (const float*)d_in[1];
    float* out = (float*)d_out;
    char*  ws  = (char*)d_ws;

    if (ws_size >= WS_NEED) {
        char*   zt     = ws + WS_ZT;
        char*   et     = ws + WS_ET;
        float*  enorm  = (float*)(ws + WS_ENORM);
        int*    cnt    = (int*)(ws + WS_CNT);
        int*    list   = (int*)(ws + WS_LIST);
        float2* cand_b = (float2*)(ws + WS_CANDB);
        int*    cand_i = (int*)(ws + WS_CANDI);

        hipLaunchKernelGGL(eprep,   dim3(256),           dim3(256), 0, stream, e, et, enorm, cnt);
        hipLaunchKernelGGL(zprep,   dim3(4096),          dim3(256), 0, stream, z, zt);
        hipLaunchKernelGGL(vq_mfma, dim3(NROW / 64 * 2), dim3(256), 0, stream,
                           zt, et, enorm, cand_b, cand_i);
        hipLaunchKernelGGL(combine, dim3(NROW / 64),     dim3(256), 0, stream,
                           cand_b, cand_i, e, out, cnt, list);
        hipLaunchKernelGGL(recheck, dim3(256),           dim3(256), 0, stream,
                           z, e, enorm, cnt, list, out);
    } else {
        float* enorm = (float*)ws;
        hipLaunchKernelGGL(enorm_kernel,   dim3(NEMB / 4), dim3(256), 0, stream, e, enorm);
        hipLaunchKernelGGL(vq_main_kernel, dim3(NROW / TM), dim3(256), 0, stream,
                           z, e, enorm, out);
    }
}

// Round 12
// 213.522 us; speedup vs baseline: 1.6617x; 1.3501x over previous
//
#include <hip/hip_runtime.h>
#include <cfloat>

typedef _Float16 half8 __attribute__((ext_vector_type(8)));
typedef float    f32x4 __attribute__((ext_vector_type(4)));
typedef unsigned int  uint;
typedef unsigned short ushort;

// Problem constants
constexpr int DIM  = 512;
constexpr int NEMB = 1024;
constexpr int HW   = 1024;
constexpr int NROW = 32 * HW;   // 32768

constexpr long long QCOUNT = (long long)32 * 512 * 32 * 32; // 16777216
constexpr long long SOFF   = QCOUNT;
constexpr long long IOFF   = SOFF + 1;

// ---------------- ws layout (bytes) ----------------
constexpr size_t WS_ZT    = 0;
constexpr size_t WS_ET    = 33554432;
constexpr size_t WS_ENORM = 34603008;
constexpr size_t WS_CNT   = 34607104;
constexpr size_t WS_LIST  = 34607360;                          // NROW*4
constexpr size_t WS_CANDB = WS_LIST + (size_t)NROW * 4;        // 2*NROW*8
constexpr size_t WS_CANDI = WS_CANDB + (size_t)2 * NROW * 8;   // 2*NROW*4
constexpr size_t WS_NEED  = WS_CANDI + (size_t)2 * NROW * 4;

// fp16 single-pass distance error: std ~0.018 (sigma_diff ~0.025).
// DELTA = 0.25 = 10 sigma -> P(flip) ~ 7.6e-24 per pair, ~2e-16 overall.
constexpr float DELTA = 0.25f;

// ---------------- helpers ----------------
__device__ __forceinline__ void gld16(const void* g, void* l) {
    __builtin_amdgcn_global_load_lds(
        (const __attribute__((address_space(1))) void*)g,
        (__attribute__((address_space(3))) void*)l, 16, 0, 0);
}
union PKH8 { half8 v; _Float16 h[8]; };

// granule swizzle for 64B-row tiles (4 x 16B granules): proven ~0 conflicts (r7-r11)
__device__ __forceinline__ int swz_slot(int r, int g) {
    return g ^ ((r >> 1) & 3);
}

// ---------------- P1: e -> et fp16 tiles + enorm + cnt zero ---------------
__global__ __launch_bounds__(256) void eprep(const float* __restrict__ e,
                                             char* __restrict__ et,
                                             float* __restrict__ enorm,
                                             int* __restrict__ cnt) {
    if (blockIdx.x == 0 && threadIdx.x == 0) *cnt = 0;
    int gid = blockIdx.x * 256 + threadIdx.x;  // 0..65535
    int ke  = gid >> 6;                        // embedding row (wave-aligned)
    int kbg = gid & 63;                        // 16B-granule (= lane)
    const float* src = e + (size_t)ke * DIM + kbg * 8;
    PKH8 h;
    float s = 0.f;
    #pragma unroll
    for (int j = 0; j < 8; ++j) {
        float v = src[j];
        h.h[j] = (_Float16)v;   // RNE
        s += v * v;
    }
    int nc = ke >> 7, r = ke & 127, kc = kbg >> 2, g = kbg & 3;
    size_t byte = ((size_t)(nc * 16 + kc)) * 8192 + (size_t)r * 64
                + ((size_t)swz_slot(r, g) << 4);
    *reinterpret_cast<half8*>(et + byte) = h.v;
    #pragma unroll
    for (int off = 32; off > 0; off >>= 1) s += __shfl_down(s, off, 64);
    if (kbg == 0) enorm[ke] = s;
}

// ---------------- P2: z -> zt fp16 swizzled 64x32 tiles (transpose) -------
__global__ __launch_bounds__(256) void zprep(const float* __restrict__ z,
                                             char* __restrict__ zt) {
    __shared__ float ls[64][65];
    const int bx = blockIdx.x;
    const int mb = bx >> 3, kcc = bx & 7;      // kcc: 64-channel group
    const int n0 = mb * 64;
    const int b  = n0 >> 10;
    const int hw0 = n0 & (HW - 1);
    const int t = threadIdx.x;
    const int c4 = t >> 6, lane = t & 63;
    #pragma unroll
    for (int rnd = 0; rnd < 16; ++rnd) {
        int cl = c4 + rnd * 4;
        ls[cl][lane] = z[((size_t)(b * DIM + kcc * 64 + cl)) * HW + hw0 + lane];
    }
    __syncthreads();
    for (int g = t; g < 512; g += 256) {
        int r = g >> 3, kbl = g & 7;
        PKH8 h;
        #pragma unroll
        for (int jj = 0; jj < 8; ++jj) h.h[jj] = (_Float16)ls[kbl * 8 + jj][r];
        int kc_l = kbl >> 2, gg = kbl & 3;
        size_t tile = (size_t)mb * 16 + kcc * 2 + kc_l;
        size_t byte = tile * 4096 + (size_t)r * 64 + ((size_t)swz_slot(r, gg) << 4);
        *reinterpret_cast<half8*>(zt + byte) = h.v;
    }
}

// ---------------- Main: counted-vmcnt depth-3 pipeline (T3/T4) -------------
#define VQ_STAGE(SS)                                                           \
  {                                                                            \
    const int kc_ = (SS) & 15;                                                 \
    const size_t tB_ = ((size_t)((half * 4 + ((SS) >> 4)) * 16 + kc_)) * 8192; \
    char* dst_ = smem + ((SS) % 3) * 12288;                                    \
    gld16(zt + zbase + (size_t)kc_ * 4096 + toff, dst_ + toff);                \
    gld16(et + tB_ + toff,        dst_ + 4096 + toff);                         \
    gld16(et + tB_ + 4096 + toff, dst_ + 8192 + toff);                         \
  }

#define VQ_STEP(S, VMLIT)                                                      \
  {                                                                            \
    asm volatile("s_waitcnt vmcnt(" VMLIT ")" ::: "memory");                   \
    __builtin_amdgcn_s_barrier();                                              \
    const char* buf_ = smem + ((S) % 3) * 12288;                               \
    half8 ah0 = *reinterpret_cast<const half8*>(buf_ + aoff0);                 \
    half8 ah1 = *reinterpret_cast<const half8*>(buf_ + aoff1);                 \
    half8 bh0 = *reinterpret_cast<const half8*>(buf_ + 4096 + boff0);          \
    half8 bh1 = *reinterpret_cast<const half8*>(buf_ + 4096 + boff1);          \
    half8 bh2 = *reinterpret_cast<const half8*>(buf_ + 4096 + boff2);          \
    half8 bh3 = *reinterpret_cast<const half8*>(buf_ + 4096 + boff3);          \
    asm volatile("s_waitcnt lgkmcnt(0)" ::: "memory");                         \
    __builtin_amdgcn_sched_barrier(0);                                         \
    __builtin_amdgcn_s_barrier();                                              \
    if ((S) + 3 < 64) VQ_STAGE((S) + 3);                                       \
    acc[0][0] = __builtin_amdgcn_mfma_f32_16x16x32_f16(ah0, bh0, acc[0][0], 0, 0, 0); \
    acc[0][1] = __builtin_amdgcn_mfma_f32_16x16x32_f16(ah0, bh1, acc[0][1], 0, 0, 0); \
    acc[0][2] = __builtin_amdgcn_mfma_f32_16x16x32_f16(ah0, bh2, acc[0][2], 0, 0, 0); \
    acc[0][3] = __builtin_amdgcn_mfma_f32_16x16x32_f16(ah0, bh3, acc[0][3], 0, 0, 0); \
    acc[1][0] = __builtin_amdgcn_mfma_f32_16x16x32_f16(ah1, bh0, acc[1][0], 0, 0, 0); \
    acc[1][1] = __builtin_amdgcn_mfma_f32_16x16x32_f16(ah1, bh1, acc[1][1], 0, 0, 0); \
    acc[1][2] = __builtin_amdgcn_mfma_f32_16x16x32_f16(ah1, bh2, acc[1][2], 0, 0, 0); \
    acc[1][3] = __builtin_amdgcn_mfma_f32_16x16x32_f16(ah1, bh3, acc[1][3], 0, 0, 0); \
    if (((S) & 15) == 15) {                                                    \
      const int ncl_ = ((S) >> 4) * 128;                                       \
      _Pragma("unroll")                                                        \
      for (int n = 0; n < 4; ++n) {                                            \
        const int lcol = ncl_ + wc * 64 + n * 16 + lr;                         \
        const float en = enorm_l[lcol];                                        \
        const int col = half * 512 + lcol;                                     \
        _Pragma("unroll")                                                      \
        for (int m = 0; m < 2; ++m) {                                          \
          _Pragma("unroll")                                                    \
          for (int q = 0; q < 4; ++q) {                                        \
            float dv = en - 2.0f * acc[m][n][q];                               \
            int sl = m * 4 + q;                                                \
            if (dv < b1v[sl]) { b2v[sl] = b1v[sl]; b1v[sl] = dv; i1v[sl] = col; } \
            else if (dv < b2v[sl]) b2v[sl] = dv;                               \
          }                                                                    \
        }                                                                      \
      }                                                                        \
      _Pragma("unroll")                                                        \
      for (int m = 0; m < 2; ++m)                                              \
        _Pragma("unroll")                                                      \
        for (int n = 0; n < 4; ++n) acc[m][n] = (f32x4)(0.f);                  \
    }                                                                          \
  }

__global__ __launch_bounds__(256, 4) void vq_mfma(const char* __restrict__ zt,
                                                  const char* __restrict__ et,
                                                  const float* __restrict__ enorm,
                                                  float2* __restrict__ cand_b,
                                                  int* __restrict__ cand_i) {
    __shared__ __align__(16) char smem[36864];   // 3 x 12KB stage ring
    __shared__ float enorm_l[512];

    const int t = threadIdx.x;
    const int w = t >> 6, l = t & 63;
    const int lr = l & 15, hg = l >> 4;          // hg = k-granule 0..3
    const int wr = w >> 1;                        // rows wr*32
    const int wc = w & 1;                         // cols wc*64
    const int bid = blockIdx.x;
    const int mb = bid >> 1;                      // 0..511
    const int half = bid & 1;                     // embedding half
    const int n0 = mb * 64;

    const int swz = swz_slot(lr, hg) << 4;
    const int aoff0 = (wr * 32 + lr) * 64 + swz;
    const int aoff1 = (wr * 32 + 16 + lr) * 64 + swz;
    const int boff0 = (wc * 64 + lr) * 64 + swz;
    const int boff1 = (wc * 64 + 16 + lr) * 64 + swz;
    const int boff2 = (wc * 64 + 32 + lr) * 64 + swz;
    const int boff3 = (wc * 64 + 48 + lr) * 64 + swz;

    // stage this half's enorm to LDS (keeps in-loop VMEM = gld16 only,
    // so the counted vmcnt stays exact)
    enorm_l[t]       = enorm[half * 512 + t];
    enorm_l[t + 256] = enorm[half * 512 + t + 256];
    __syncthreads();

    float b1v[8], b2v[8]; int i1v[8];
    #pragma unroll
    for (int s = 0; s < 8; ++s) { b1v[s] = FLT_MAX; b2v[s] = FLT_MAX; i1v[s] = 0; }

    const size_t zbase = (size_t)mb * 16 * 4096;
    const int toff = t * 16;

    f32x4 acc[2][4];
    #pragma unroll
    for (int m = 0; m < 2; ++m)
        #pragma unroll
        for (int n = 0; n < 4; ++n) acc[m][n] = (f32x4)(0.f);

    // prologue: issue stages 0..2 (9 VMEM instrs in flight)
    VQ_STAGE(0);
    VQ_STAGE(1);
    VQ_STAGE(2);

    for (int s = 0; s < 62; ++s) {
        VQ_STEP(s, "6");
    }
    VQ_STEP(62, "3");
    VQ_STEP(63, "0");

    // ---- butterfly over the 16 col-lanes sharing each row
    #pragma unroll
    for (int s = 0; s < 8; ++s) {
        #pragma unroll
        for (int off = 1; off <= 8; off <<= 1) {
            float ob1 = __shfl_xor(b1v[s], off, 64);
            int   oi1 = __shfl_xor(i1v[s], off, 64);
            float ob2 = __shfl_xor(b2v[s], off, 64);
            if (ob1 < b1v[s] || (ob1 == b1v[s] && oi1 < i1v[s])) {
                b2v[s] = fminf(b1v[s], ob2);
                b1v[s] = ob1; i1v[s] = oi1;
            } else {
                b2v[s] = fminf(b2v[s], ob1);
            }
        }
    }
    // ---- block reduction across the 2 col-waves (overlay on dead stage ring)
    __syncthreads();
    float* red_b1 = reinterpret_cast<float*>(smem);          // [64][2]
    float* red_b2 = reinterpret_cast<float*>(smem + 512);    // [64][2]
    int*   red_i1 = reinterpret_cast<int*>  (smem + 1024);   // [64][2]
    if (lr == 0) {
        #pragma unroll
        for (int s = 0; s < 8; ++s) {
            int row = wr * 32 + (s >> 2) * 16 + hg * 4 + (s & 3);
            red_b1[row * 2 + wc] = b1v[s];
            red_b2[row * 2 + wc] = b2v[s];
            red_i1[row * 2 + wc] = i1v[s];
        }
    }
    __syncthreads();
    if (t < 64) {
        float a1 = red_b1[t * 2], a2 = red_b2[t * 2]; int ai = red_i1[t * 2];
        float c1 = red_b1[t * 2 + 1], c2 = red_b2[t * 2 + 1]; int ci = red_i1[t * 2 + 1];
        float B1, B2; int I1;
        if (c1 < a1 || (c1 == a1 && ci < ai)) { B1 = c1; I1 = ci; B2 = fminf(a1, c2); }
        else                                   { B1 = a1; I1 = ai; B2 = fminf(a2, c1); }
        cand_b[(size_t)half * NROW + n0 + t] = make_float2(B1, B2);
        cand_i[(size_t)half * NROW + n0 + t] = I1;
    }
}

// ---------------- Combine: merge halves, write idx, flag, gather -----------
__global__ __launch_bounds__(256) void combine(const float2* __restrict__ cand_b,
                                               const int* __restrict__ cand_i,
                                               const float* __restrict__ e,
                                               float* __restrict__ out,
                                               int* __restrict__ cnt,
                                               int* __restrict__ list) {
    __shared__ int idx_f[64];
    const int t = threadIdx.x;
    const int n0 = blockIdx.x * 64;
    if (t < 64) {
        const int row = n0 + t;
        float2 a = cand_b[row];
        float2 c = cand_b[NROW + row];
        int ai = cand_i[row];
        int ci = cand_i[NROW + row];
        float B1, B2; int I1;
        // half0 indices < half1 indices: strict < keeps lowest-index on ties
        if (c.x < a.x) { B1 = c.x; I1 = ci; B2 = fminf(a.x, c.y); }
        else           { B1 = a.x; I1 = ai; B2 = fminf(a.y, c.x); }
        idx_f[t] = I1;
        out[IOFF + row] = (float)I1;
        if (B2 - B1 < DELTA) {
            int pos = atomicAdd(cnt, 1);
            list[pos] = row;
        }
    }
    if (blockIdx.x == 0 && t == 0) out[SOFF] = 0.0f;
    __syncthreads();

    // gather: out[b][c][hw0+row] = e[idx[row]][c]
    const int b   = n0 >> 10;
    const int hw0 = n0 & (HW - 1);
    const int row4 = (t & 15) * 4;
    const int i0 = idx_f[row4 + 0];
    const int i1 = idx_f[row4 + 1];
    const int i2 = idx_f[row4 + 2];
    const int i3 = idx_f[row4 + 3];
    #pragma unroll 4
    for (int p = 0; p < 32; ++p) {
        int c = (t >> 4) + (p << 4);
        float4 v;
        v.x = e[(size_t)i0 * DIM + c];
        v.y = e[(size_t)i1 * DIM + c];
        v.z = e[(size_t)i2 * DIM + c];
        v.w = e[(size_t)i3 * DIM + c];
        *reinterpret_cast<float4*>(&out[((size_t)(b * DIM + c)) * HW + hw0 + row4]) = v;
    }
}

// ---------------- Recheck: 4-row-batched exact fp32 re-scan ----------------
// Grid 1024 (grid-stride): 2-4 blocks/CU when count ~1-4k -> latency hiding.
__global__ __launch_bounds__(256) void recheck(const float* __restrict__ z,
                                               const float* __restrict__ e,
                                               const float* __restrict__ enorm,
                                               const int* __restrict__ cnt,
                                               const int* __restrict__ list,
                                               float* __restrict__ out) {
    __shared__ float zrow[4][512];
    __shared__ float rb[256];
    __shared__ int   ri[256];
    __shared__ int   fidx[4];
    const int t = threadIdx.x;
    const int count = *cnt;
    const int ngrp = (count + 3) >> 2;
    for (int g = blockIdx.x; g < ngrp; g += gridDim.x) {
        const int base = g * 4;
        const int nr = min(4, count - base);
        __syncthreads();
        for (int r = 0; r < nr; ++r) {
            const int row = list[base + r];
            const int b = row >> 10, hw = row & (HW - 1);
            zrow[r][t]       = z[((size_t)(b * DIM + t))       * HW + hw];
            zrow[r][t + 256] = z[((size_t)(b * DIM + t + 256)) * HW + hw];
        }
        __syncthreads();
        float best[4]; int bi[4];
        #pragma unroll
        for (int r = 0; r < 4; ++r) { best[r] = FLT_MAX; bi[r] = 0; }
        #pragma unroll
        for (int p = 0; p < 4; ++p) {
            const int ke = t + p * 256;
            const float4* ep = reinterpret_cast<const float4*>(e + (size_t)ke * DIM);
            float d0 = 0.f, d1 = 0.f, d2 = 0.f, d3 = 0.f;
            const float4* z0 = reinterpret_cast<const float4*>(zrow[0]);
            const float4* z1 = reinterpret_cast<const float4*>(zrow[1]);
            const float4* z2 = reinterpret_cast<const float4*>(zrow[2]);
            const float4* z3 = reinterpret_cast<const float4*>(zrow[3]);
            for (int c = 0; c < 128; ++c) {
                float4 ev = ep[c];
                float4 a0 = z0[c], a1 = z1[c], a2 = z2[c], a3 = z3[c];
                d0 += ev.x*a0.x + ev.y*a0.y + ev.z*a0.z + ev.w*a0.w;
                d1 += ev.x*a1.x + ev.y*a1.y + ev.z*a1.z + ev.w*a1.w;
                d2 += ev.x*a2.x + ev.y*a2.y + ev.z*a2.z + ev.w*a2.w;
                d3 += ev.x*a3.x + ev.y*a3.y + ev.z*a3.z + ev.w*a3.w;
            }
            const float en = enorm[ke];
            float dd[4] = { en - 2.f*d0, en - 2.f*d1, en - 2.f*d2, en - 2.f*d3 };
            #pragma unroll
            for (int r = 0; r < 4; ++r)
                if (dd[r] < best[r]) { best[r] = dd[r]; bi[r] = ke; }
        }
        for (int r = 0; r < nr; ++r) {
            rb[t] = best[r]; ri[t] = bi[r];
            __syncthreads();
            #pragma unroll
            for (int s = 128; s > 0; s >>= 1) {
                if (t < s) {
                    float ov = rb[t + s]; int oi = ri[t + s];
                    if (ov < rb[t] || (ov == rb[t] && oi < ri[t])) {
                        rb[t] = ov; ri[t] = oi;
                    }
                }
                __syncthreads();
            }
            if (t == 0) {
                fidx[r] = ri[0];
                out[IOFF + list[base + r]] = (float)ri[0];
            }
            __syncthreads();
        }
        for (int r = 0; r < nr; ++r) {
            const int row = list[base + r];
            const int b = row >> 10, hw = row & (HW - 1);
            const int fbi = fidx[r];
            out[((size_t)(b * DIM + t))       * HW + hw] = e[(size_t)fbi * DIM + t];
            out[((size_t)(b * DIM + t + 256)) * HW + hw] = e[(size_t)fbi * DIM + t + 256];
        }
    }
}

// ======================= fp32 fallback path (round-2, proven) ================
constexpr int TM = 64;
constexpr int TN = 256;
constexpr int KC = 32;
constexpr int ZST = 68;
constexpr int EST = 260;

union F4 { float4 v; float f[4]; };

__global__ __launch_bounds__(256) void enorm_kernel(const float* __restrict__ e,
                                                    float* __restrict__ enorm) {
    int gid  = blockIdx.x * 256 + threadIdx.x;
    int wave = gid >> 6;
    int lane = gid & 63;
    if (wave >= NEMB) return;
    const float* row = e + (size_t)wave * DIM;
    float4 a = *reinterpret_cast<const float4*>(row + lane * 8);
    float4 b = *reinterpret_cast<const float4*>(row + lane * 8 + 4);
    float s = a.x*a.x + a.y*a.y + a.z*a.z + a.w*a.w
            + b.x*b.x + b.y*b.y + b.z*b.z + b.w*b.w;
    #pragma unroll
    for (int off = 32; off > 0; off >>= 1) s += __shfl_down(s, off, 64);
    if (lane == 0) enorm[wave] = s;
}

__global__ __launch_bounds__(256) void vq_main_kernel(const float* __restrict__ z,
                                                      const float* __restrict__ e,
                                                      const float* __restrict__ enorm,
                                                      float* __restrict__ out) {
    __shared__ float zs[KC][ZST];
    __shared__ float es[KC][EST];
    __shared__ float enorm_l[NEMB];
    __shared__ int   idx_f[TM];

    const int t   = threadIdx.x;
    const int n0  = blockIdx.x * TM;
    const int b   = n0 >> 10;
    const int hw0 = n0 & (HW - 1);
    const float* zb = z + ((size_t)b * DIM) * HW + hw0;

    #pragma unroll
    for (int i = 0; i < 4; ++i) enorm_l[t + i * 256] = enorm[t + i * 256];

    const int rg = t >> 5;
    const int cg = t & 31;

    float best[8];
    int   bidx[8];
    #pragma unroll
    for (int i = 0; i < 8; ++i) { best[i] = FLT_MAX; bidx[i] = 0; }

    const int z_r4 = (t & 15) * 4;
    const int z_c  = t >> 4;
    const int e_ke = t >> 3;
    const int e_c4 = t & 7;

    for (int nc = 0; nc < NEMB / TN; ++nc) {
        const int k0 = nc * TN;
        float acc[8][8];
        #pragma unroll
        for (int mi = 0; mi < 8; ++mi)
            #pragma unroll
            for (int nj = 0; nj < 8; ++nj) acc[mi][nj] = 0.f;

        for (int kc = 0; kc < DIM / KC; ++kc) {
            const int c0 = kc * KC;
            __syncthreads();
            #pragma unroll
            for (int p = 0; p < 2; ++p) {
                int c = z_c + p * 16;
                float4 v = *reinterpret_cast<const float4*>(zb + (size_t)(c0 + c) * HW + z_r4);
                *reinterpret_cast<float4*>(&zs[c][z_r4]) = v;
            }
            #pragma unroll
            for (int p = 0; p < 8; ++p) {
                int ke = e_ke + p * 32;
                float4 v = *reinterpret_cast<const float4*>(e + (size_t)(k0 + ke) * DIM + c0 + e_c4 * 4);
                es[e_c4 * 4 + 0][ke] = v.x;
                es[e_c4 * 4 + 1][ke] = v.y;
                es[e_c4 * 4 + 2][ke] = v.z;
                es[e_c4 * 4 + 3][ke] = v.w;
            }
            __syncthreads();
            #pragma unroll
            for (int kk = 0; kk < KC; ++kk) {
                F4 zf0, zf1, ef0, ef1;
                zf0.v = *reinterpret_cast<const float4*>(&zs[kk][rg * 8]);
                zf1.v = *reinterpret_cast<const float4*>(&zs[kk][rg * 8 + 4]);
                ef0.v = *reinterpret_cast<const float4*>(&es[kk][cg * 4]);
                ef1.v = *reinterpret_cast<const float4*>(&es[kk][128 + cg * 4]);
                #pragma unroll
                for (int mi = 0; mi < 4; ++mi) {
                    #pragma unroll
                    for (int nj = 0; nj < 4; ++nj) {
                        acc[mi][nj]         += zf0.f[mi] * ef0.f[nj];
                        acc[mi][nj + 4]     += zf0.f[mi] * ef1.f[nj];
                        acc[mi + 4][nj]     += zf1.f[mi] * ef0.f[nj];
                        acc[mi + 4][nj + 4] += zf1.f[mi] * ef1.f[nj];
                    }
                }
            }
        }
        #pragma unroll
        for (int mi = 0; mi < 8; ++mi) {
            #pragma unroll
            for (int nj = 0; nj < 8; ++nj) {
                int col = k0 + (nj < 4 ? cg * 4 + nj : 128 + cg * 4 + (nj - 4));
                float dv = enorm_l[col] - 2.0f * acc[mi][nj];
                if (dv < best[mi]) { best[mi] = dv; bidx[mi] = col; }
            }
        }
    }

    __syncthreads();
    float* best_l = reinterpret_cast<float*>(es);
    int*   idx_l  = reinterpret_cast<int*>(reinterpret_cast<char*>(es) + (size_t)TM * 33 * 4);
    #pragma unroll
    for (int mi = 0; mi < 8; ++mi) {
        int row = rg * 8 + mi;
        best_l[row * 33 + cg] = best[mi];
        idx_l[row * 33 + cg]  = bidx[mi];
    }
    __syncthreads();
    if (t < TM) {
        float bv = best_l[t * 33];
        int   bi = idx_l[t * 33];
        #pragma unroll
        for (int c = 1; c < 32; ++c) {
            float v  = best_l[t * 33 + c];
            int   ix = idx_l[t * 33 + c];
            if (v < bv || (v == bv && ix < bi)) { bv = v; bi = ix; }
        }
        idx_f[t] = bi;
        out[IOFF + n0 + t] = (float)bi;
    }
    if (blockIdx.x == 0 && t == 0) out[SOFF] = 0.0f;
    __syncthreads();

    const int row4 = (t & 15) * 4;
    const int i0 = idx_f[row4 + 0];
    const int i1 = idx_f[row4 + 1];
    const int i2 = idx_f[row4 + 2];
    const int i3 = idx_f[row4 + 3];
    #pragma unroll 4
    for (int p = 0; p < 32; ++p) {
        int c = (t >> 4) + (p << 4);
        float4 v;
        v.x = e[(size_t)i0 * DIM + c];
        v.y = e[(size_t)i1 * DIM + c];
        v.z = e[(size_t)i2 * DIM + c];
        v.w = e[(size_t)i3 * DIM + c];
        *reinterpret_cast<float4*>(&out[((size_t)(b * DIM + c)) * HW + hw0 + row4]) = v;
    }
}

// ---------------- host launcher ----------------
extern "C" void kernel_launch(void* const* d_in, const int* in_sizes, int n_in,
                              void* d_out, int out_size, void* d_ws, size_t ws_size,
                              hipStream_t stream) {
    const float* z = (const float*)d_in[0];
    const float* e = (const float*)d_in[1];
    float* out = (float*)d_out;
    char*  ws  = (char*)d_ws;

    if (ws_size >= WS_NEED) {
        char*   zt     = ws + WS_ZT;
        char*   et     = ws + WS_ET;
        float*  enorm  = (float*)(ws + WS_ENORM);
        int*    cnt    = (int*)(ws + WS_CNT);
        int*    list   = (int*)(ws + WS_LIST);
        float2* cand_b = (float2*)(ws + WS_CANDB);
        int*    cand_i = (int*)(ws + WS_CANDI);

        hipLaunchKernelGGL(eprep,   dim3(256),           dim3(256), 0, stream, e, et, enorm, cnt);
        hipLaunchKernelGGL(zprep,   dim3(4096),          dim3(256), 0, stream, z, zt);
        hipLaunchKernelGGL(vq_mfma, dim3(NROW / 64 * 2), dim3(256), 0, stream,
                           zt, et, enorm, cand_b, cand_i);
        hipLaunchKernelGGL(combine, dim3(NROW / 64),     dim3(256), 0, stream,
                           cand_b, cand_i, e, out, cnt, list);
        hipLaunchKernelGGL(recheck, dim3(1024),          dim3(256), 0, stream,
                           z, e, enorm, cnt, list, out);
    } else {
        float* enorm = (float*)ws;
        hipLaunchKernelGGL(enorm_kernel,   dim3(NEMB / 4), dim3(256), 0, stream, e, enorm);
        hipLaunchKernelGGL(vq_main_kernel, dim3(NROW / TM), dim3(256), 0, stream,
                           z, e, enorm, out);
    }
}